// Round 2
// baseline (736.452 us; speedup 1.0000x reference)
//
#include <hip/hip_runtime.h>
#include <math.h>

#define T_TOK 2048
#define HDIM  4096
#define QKVN  6144
#define NHEADS 32
#define HD    128
#define KV_OFF 4096
#define V_OFF  5120
#define SCALE 0.08838834764831843f

typedef __attribute__((ext_vector_type(8))) short short8;
typedef __attribute__((ext_vector_type(4))) float f32x4;
typedef __attribute__((ext_vector_type(16))) float f32x16;

__device__ __forceinline__ ushort f2bf(float f) {
    union { float f; unsigned u; } v; v.f = f;
    unsigned r = v.u + 0x7FFFu + ((v.u >> 16) & 1u);   // RNE
    return (ushort)(r >> 16);
}

// ---------------------------------------------------------------------------
// 256x256 8-phase bf16 MFMA GEMM, C[M,N] = A[M,:]*B^T[N,:], row stride LDK,
// K-extent KC (split-K via blockIdx.y; kz=0 -> C0, kz=1 -> C1).
// 8 waves (2M x 4N), BK=64, double-buffered LDS (128 KiB).
// Register loads pipelined ONE PHASE AHEAD (single-copy regs; a0/bq01 of t+1
// are read in ph4(t) where their old values are dead). Read distribution
// 4/4/4/12 ds_read_b128 per phase. lgkmcnt(0) before every phase-end barrier
// closes the ds_read vs incoming global_load_lds WAR window.
// Steady state: 14 loads in flight at ph4's vmcnt(6) -> retires tile t+1.
// ---------------------------------------------------------------------------
template <int N_, int LDK, int KC>
__global__ __launch_bounds__(512, 2) void gemm_bf16_8ph(const ushort* __restrict__ A,
                                                        const ushort* __restrict__ B,
                                                        float* __restrict__ C0,
                                                        float* __restrict__ C1) {
    __shared__ __attribute__((aligned(16))) ushort As[2][2][8192];  // [buf][half][128*64]
    __shared__ __attribute__((aligned(16))) ushort Bs[2][2][8192];

    constexpr int NT = KC / 64;
    constexpr int NBN = N_ / 256;

    const int kz = blockIdx.y;
    float* __restrict__ C = kz ? C1 : C0;

    const int nwgx = (int)gridDim.x;
    const int bid = (int)blockIdx.x;
    const int swz = (nwgx & 7) ? bid : ((bid & 7) * (nwgx >> 3) + (bid >> 3));  // XCD swizzle
    const int bm = (swz / NBN) * 256;
    const int bn = (swz % NBN) * 256;

    const int tid = (int)threadIdx.x;
    const int w = tid >> 6;           // 0..7
    const int l = tid & 63;
    const int hfa = w >> 2;           // A half used by this wave
    const int hfb = (w & 3) >> 1;     // B half used by this wave
    const int wbr64 = (w & 1) * 4096; // row-offset*64 within B half

    // ds-read addressing: element idx = frag*1024 + (l&15)*64 + colswz
    const int arc = (l & 15) * 64;
    const int ac0 = ((((l >> 4) << 4)) ^ ((l & 7) << 4)) >> 1;
    const int ac1 = (((1 << 6) | ((l >> 4) << 4)) ^ ((l & 7) << 4)) >> 1;

    // stage source addressing (inverse swizzle folded into per-lane col)
    const int grow = w * 8 + (l >> 3);            // 0..63
    const int gcol = ((l & 7) ^ (l >> 3)) * 8;    // element col within 64
    const ushort* Ag = A + (size_t)kz * KC + (size_t)(bm + grow) * LDK + gcol;
    const ushort* Bg = B + (size_t)kz * KC + (size_t)(bn + grow) * LDK + gcol;

    auto ldsA = (__attribute__((address_space(3))) char*)&As[0][0][0];
    auto ldsB = (__attribute__((address_space(3))) char*)&Bs[0][0][0];
    const int wsl = w * 1024;

#define STG2(ldsbase, gsrc, bufi, hfi, kt)                                                              \
    do {                                                                                                \
        __builtin_amdgcn_global_load_lds(                                                               \
            (const __attribute__((address_space(1))) void*)((gsrc) + (size_t)((hfi) * 128) * LDK + (kt) * 64),       \
            (__attribute__((address_space(3))) void*)((ldsbase) + (bufi) * 32768 + (hfi) * 16384 + wsl), 16, 0, 0);  \
        __builtin_amdgcn_global_load_lds(                                                               \
            (const __attribute__((address_space(1))) void*)((gsrc) + (size_t)((hfi) * 128 + 64) * LDK + (kt) * 64),  \
            (__attribute__((address_space(3))) void*)((ldsbase) + (bufi) * 32768 + (hfi) * 16384 + 8192 + wsl), 16, 0, 0); \
    } while (0)

    // prologue: tile0 fully, then tile1 (B-h0,B-h1,A-h0)
    STG2(ldsB, Bg, 0, 0, 0);
    STG2(ldsB, Bg, 0, 1, 0);
    STG2(ldsA, Ag, 0, 0, 0);
    STG2(ldsA, Ag, 0, 1, 0);
    STG2(ldsB, Bg, 1, 0, 1);
    STG2(ldsB, Bg, 1, 1, 1);
    STG2(ldsA, Ag, 1, 0, 1);
    asm volatile("s_waitcnt vmcnt(6)" ::: "memory");   // tile0's 8 loads done
    __builtin_amdgcn_s_barrier();

    f32x4 acc[8][4];
#pragma unroll
    for (int i = 0; i < 8; i++)
#pragma unroll
        for (int j = 0; j < 4; j++) acc[i][j] = (f32x4){0.f, 0.f, 0.f, 0.f};

    short8 a0[4][2], aH[4][2], bq01[2][2], bq23[2][2];

    // prologue register loads for tile 0 (role of ph4(t-1))
    {
        const ushort* Abuf = &As[0][hfa][0];
        const ushort* Bbuf = &Bs[0][hfb][0] + wbr64;
#pragma unroll
        for (int fi = 0; fi < 4; fi++) {
            a0[fi][0] = *(const short8*)(Abuf + fi * 1024 + arc + ac0);
            a0[fi][1] = *(const short8*)(Abuf + fi * 1024 + arc + ac1);
        }
#pragma unroll
        for (int fj = 0; fj < 2; fj++) {
            bq01[fj][0] = *(const short8*)(Bbuf + fj * 1024 + arc + ac0);
            bq01[fj][1] = *(const short8*)(Bbuf + fj * 1024 + arc + ac1);
        }
    }

    int buf = 0;
    for (int t = 0; t < NT; ++t) {
        const int nb = buf ^ 1;
        const ushort* Abuf = &As[buf][hfa][0];
        const ushort* Bbuf = &Bs[buf][hfb][0] + wbr64;
        const ushort* AbufN = &As[nb][hfa][0];
        const ushort* BbufN = &Bs[nb][hfb][0] + wbr64;

        // ---- phase 1: stage A-h1(t+1); read bq23(t); MFMA acc[0..3][0..1] ----
        if (t + 1 < NT) STG2(ldsA, Ag, nb, 1, t + 1);
#pragma unroll
        for (int fj = 0; fj < 2; fj++) {
            bq23[fj][0] = *(const short8*)(Bbuf + (fj + 2) * 1024 + arc + ac0);
            bq23[fj][1] = *(const short8*)(Bbuf + (fj + 2) * 1024 + arc + ac1);
        }
        __builtin_amdgcn_s_barrier();
        __builtin_amdgcn_s_setprio(1);
#pragma unroll
        for (int fi = 0; fi < 4; fi++)
#pragma unroll
            for (int fj = 0; fj < 2; fj++)
#pragma unroll
                for (int s = 0; s < 2; s++)
                    acc[fi][fj] = __builtin_amdgcn_mfma_f32_16x16x32_bf16(a0[fi][s], bq01[fj][s], acc[fi][fj], 0, 0, 0);
        __builtin_amdgcn_s_setprio(0);
        asm volatile("s_waitcnt lgkmcnt(0)" ::: "memory");
        __builtin_amdgcn_s_barrier();

        // ---- phase 2: stage B-h0(t+2); read aH[0..1](t); MFMA acc[0..3][2..3] ----
        if (t + 2 < NT) STG2(ldsB, Bg, buf, 0, t + 2);
#pragma unroll
        for (int fi = 0; fi < 2; fi++) {
            aH[fi][0] = *(const short8*)(Abuf + (fi + 4) * 1024 + arc + ac0);
            aH[fi][1] = *(const short8*)(Abuf + (fi + 4) * 1024 + arc + ac1);
        }
        __builtin_amdgcn_s_barrier();
        __builtin_amdgcn_s_setprio(1);
#pragma unroll
        for (int fi = 0; fi < 4; fi++)
#pragma unroll
            for (int fj = 0; fj < 2; fj++)
#pragma unroll
                for (int s = 0; s < 2; s++)
                    acc[fi][fj + 2] = __builtin_amdgcn_mfma_f32_16x16x32_bf16(a0[fi][s], bq23[fj][s], acc[fi][fj + 2], 0, 0, 0);
        __builtin_amdgcn_s_setprio(0);
        asm volatile("s_waitcnt lgkmcnt(0)" ::: "memory");
        __builtin_amdgcn_s_barrier();

        // ---- phase 3: stage B-h1(t+2); read aH[2..3](t); MFMA acc[4..7][2..3] ----
        if (t + 2 < NT) STG2(ldsB, Bg, buf, 1, t + 2);
#pragma unroll
        for (int fi = 2; fi < 4; fi++) {
            aH[fi][0] = *(const short8*)(Abuf + (fi + 4) * 1024 + arc + ac0);
            aH[fi][1] = *(const short8*)(Abuf + (fi + 4) * 1024 + arc + ac1);
        }
        __builtin_amdgcn_s_barrier();
        __builtin_amdgcn_s_setprio(1);
#pragma unroll
        for (int fi = 0; fi < 4; fi++)
#pragma unroll
            for (int fj = 0; fj < 2; fj++)
#pragma unroll
                for (int s = 0; s < 2; s++)
                    acc[fi + 4][fj + 2] = __builtin_amdgcn_mfma_f32_16x16x32_bf16(aH[fi][s], bq23[fj][s], acc[fi + 4][fj + 2], 0, 0, 0);
        __builtin_amdgcn_s_setprio(0);
        asm volatile("s_waitcnt lgkmcnt(0)" ::: "memory");
        __builtin_amdgcn_s_barrier();

        // ---- phase 4: stage A-h0(t+2); vmcnt; read a0/bq01(t+1); MFMA acc[4..7][0..1] ----
        if (t + 2 < NT) {
            STG2(ldsA, Ag, buf, 0, t + 2);
            asm volatile("s_waitcnt vmcnt(6)" ::: "memory");   // tile t+1 fully landed
        } else {
            asm volatile("s_waitcnt vmcnt(0)" ::: "memory");   // tail drain
        }
        __builtin_amdgcn_s_barrier();
        if (t + 1 < NT) {
#pragma unroll
            for (int fi = 0; fi < 4; fi++) {
                a0[fi][0] = *(const short8*)(AbufN + fi * 1024 + arc + ac0);
                a0[fi][1] = *(const short8*)(AbufN + fi * 1024 + arc + ac1);
            }
        }
        __builtin_amdgcn_s_setprio(1);
#pragma unroll
        for (int fi = 0; fi < 4; fi++)
#pragma unroll
            for (int fj = 0; fj < 2; fj++)
#pragma unroll
                for (int s = 0; s < 2; s++)
                    acc[fi + 4][fj] = __builtin_amdgcn_mfma_f32_16x16x32_bf16(aH[fi][s], bq01[fj][s], acc[fi + 4][fj], 0, 0, 0);
        __builtin_amdgcn_s_setprio(0);
        if (t + 1 < NT) {
#pragma unroll
            for (int fj = 0; fj < 2; fj++) {
                bq01[fj][0] = *(const short8*)(BbufN + fj * 1024 + arc + ac0);
                bq01[fj][1] = *(const short8*)(BbufN + fj * 1024 + arc + ac1);
            }
        }
        asm volatile("s_waitcnt lgkmcnt(0)" ::: "memory");
        __builtin_amdgcn_s_barrier();

        buf = nb;
    }
#undef STG2

    // epilogue: C-frag layout col=l&15, row=(l>>4)*4+r
    const int cn = bn + (w & 3) * 64 + (l & 15);
    const int rm = bm + hfa * 128 + ((l >> 4) << 2);
#pragma unroll
    for (int fi = 0; fi < 8; fi++)
#pragma unroll
        for (int fj = 0; fj < 4; fj++)
#pragma unroll
            for (int r = 0; r < 4; r++)
                C[(size_t)(rm + 16 * fi + r) * N_ + cn + 16 * fj] = acc[fi][fj][r];
}

// ---------------------------------------------------------------------------
__global__ __launch_bounds__(256) void add_f32(float* __restrict__ out,
                                               const float* __restrict__ p) {
    const int i = (blockIdx.x * 256 + threadIdx.x) * 4;
    float4 a = *(const float4*)(out + i);
    float4 b = *(const float4*)(p + i);
    a.x += b.x; a.y += b.y; a.z += b.z; a.w += b.w;
    *(float4*)(out + i) = a;
}

// ---------------------------------------------------------------------------
__global__ __launch_bounds__(256) void cast_bf16(const float* __restrict__ in,
                                                 ushort* __restrict__ outp) {
    const int i = (blockIdx.x * 256 + threadIdx.x) * 4;
    float4 v = *(const float4*)(in + i);
    ushort4 o = {f2bf(v.x), f2bf(v.y), f2bf(v.z), f2bf(v.w)};
    *(ushort4*)(outp + i) = o;
}

// ---------------------------------------------------------------------------
template <int K_, int N_>
__global__ __launch_bounds__(256) void transpose_cast(const float* __restrict__ W,
                                                      ushort* __restrict__ WT) {
    __shared__ float T[32 * 65];
    const int k0 = blockIdx.y * 32;
    const int n0 = blockIdx.x * 64;
    const int x = threadIdx.x & 63;
    const int y = threadIdx.x >> 6;
#pragma unroll
    for (int p = 0; p < 8; p++) {
        const int kk = p * 4 + y;
        T[kk * 65 + x] = W[(size_t)(k0 + kk) * N_ + n0 + x];
    }
    __syncthreads();
#pragma unroll
    for (int q = 0; q < 4; q++) {
        const int nl = q * 16 + (threadIdx.x >> 4);
        const int k2 = (threadIdx.x & 15) * 2;
        ushort2 o = {f2bf(T[k2 * 65 + nl]), f2bf(T[(k2 + 1) * 65 + nl])};
        *(ushort2*)&WT[(size_t)(n0 + nl) * K_ + k0 + k2] = o;
    }
}

// ---------------------------------------------------------------------------
// NeoX RoPE fp32 qkv -> bf16 qkB for q (scaled) and k heads. v cols unwritten.
// ---------------------------------------------------------------------------
__global__ __launch_bounds__(256) void rope_cast(const int* __restrict__ pos,
                                                 const float* __restrict__ qkv,
                                                 ushort* __restrict__ qkB) {
    const int t = blockIdx.x;
    const int slot = blockIdx.y * 4 + (threadIdx.x >> 6);   // 0..39
    const int d = threadIdx.x & 63;
    const float p = (float)pos[t];
    const float invf = exp2f(-(float)d * (19.931568569324174f / 64.0f));
    const float f = p * invf;
    const float c = cosf(f), s = sinf(f);
    const float sc = (slot < 32) ? SCALE : 1.0f;
    const float* base = qkv + (size_t)t * QKVN + slot * HD;
    ushort* ob = qkB + (size_t)t * QKVN + slot * HD;
    const float x1 = base[d];
    const float x2 = base[d + 64];
    ob[d]      = f2bf((x1 * c - x2 * s) * sc);
    ob[d + 64] = f2bf((x2 * c + x1 * s) * sc);
}

// ---------------------------------------------------------------------------
// V transpose: qkv fp32 v-part [t][5120 + c] -> Vt bf16 [c][t], c = kvh*128+d.
// ---------------------------------------------------------------------------
__global__ __launch_bounds__(256) void vt_cast(const float* __restrict__ qkv,
                                               ushort* __restrict__ Vt) {
    __shared__ float tile[32][33];
    const int t0 = blockIdx.x * 32;
    const int c0 = blockIdx.y * 32;
    const int tx = threadIdx.x & 31;
    const int ty = threadIdx.x >> 5;   // 0..7
#pragma unroll
    for (int i = 0; i < 4; i++) {
        const int tt = ty + 8 * i;
        tile[tt][tx] = qkv[(size_t)(t0 + tt) * QKVN + V_OFF + c0 + tx];
    }
    __syncthreads();
#pragma unroll
    for (int i = 0; i < 4; i++) {
        const int dd = ty + 8 * i;
        Vt[(size_t)(c0 + dd) * 2048 + t0 + tx] = f2bf(tile[tx][dd]);
    }
}

// ---------------------------------------------------------------------------
// MFMA flash attention, double-buffered staging (raw s_barrier + vmcnt(4)):
// each tile's 4 global_load_lds have a full compute phase to land.
// ---------------------------------------------------------------------------
__global__ __launch_bounds__(256, 2) void flash_attn_mfma(
        const ushort* __restrict__ qkB,
        const ushort* __restrict__ Vt,
        ushort* __restrict__ attnB) {
    __shared__ ushort Kf[2][8 * 512];   // [buf][8 frags x 1024 B]
    __shared__ ushort Vf[2][8 * 512];

    const int b = blockIdx.x;              // 512
    const int half = b >> 8;
    const int rest = b & 255;
    const int h = rest >> 3;               // 0..31
    const int q8 = rest & 7;
    const int qi = half ? (15 - q8) : q8;  // 0..15, paired for balance
    const int kvh = h >> 2;

    const int tid = threadIdx.x;
    const int w = tid >> 6;
    const int l = tid & 63;
    const int l31 = l & 31;
    const int hf = l >> 5;

    const int qg = qi * 128 + w * 32 + l31;   // this lane's q row

    short8 qf[8];
    {
        const ushort* qrow = qkB + (size_t)qg * QKVN + h * HD + hf * 8;
#pragma unroll
        for (int kt = 0; kt < 8; kt++)
            qf[kt] = *(const short8*)(qrow + kt * 16);
    }

    f32x16 O[4];
#pragma unroll
    for (int dt = 0; dt < 4; dt++)
#pragma unroll
        for (int r = 0; r < 16; r++) O[dt][r] = 0.f;
    float mcur = -INFINITY, lcur = 0.f;

    const ushort* kbase = qkB + (size_t)l31 * QKVN + KV_OFF + kvh * HD + (2 * w) * 16 + hf * 8;
    const ushort* vbase = Vt + ((size_t)(kvh * 128 + w * 32 + l31)) * 2048 + hf * 8;

    auto ldsK = (__attribute__((address_space(3))) char*)&Kf[0][0];
    auto ldsV = (__attribute__((address_space(3))) char*)&Vf[0][0];

    const int nst = 4 * qi + 4;
    const int mylast = 4 * qi + w;

#define AST(s, bb)                                                                               \
    do {                                                                                         \
        const ushort* kg = kbase + (size_t)(s) * 32 * QKVN;                                      \
        __builtin_amdgcn_global_load_lds(                                                        \
            (const __attribute__((address_space(1))) void*)kg,                                   \
            (__attribute__((address_space(3))) void*)(ldsK + (bb) * 8192 + (2 * w) * 1024), 16, 0, 0);      \
        __builtin_amdgcn_global_load_lds(                                                        \
            (const __attribute__((address_space(1))) void*)(kg + 16),                            \
            (__attribute__((address_space(3))) void*)(ldsK + (bb) * 8192 + (2 * w + 1) * 1024), 16, 0, 0);  \
        const ushort* vg = vbase + (s) * 32;                                                     \
        __builtin_amdgcn_global_load_lds(                                                        \
            (const __attribute__((address_space(1))) void*)vg,                                   \
            (__attribute__((address_space(3))) void*)(ldsV + (bb) * 8192 + (2 * w) * 1024), 16, 0, 0);      \
        __builtin_amdgcn_global_load_lds(                                                        \
            (const __attribute__((address_space(1))) void*)(vg + 16),                            \
            (__attribute__((address_space(3))) void*)(ldsV + (bb) * 8192 + (2 * w + 1) * 1024), 16, 0, 0);  \
    } while (0)

    AST(0, 0);   // prologue: stage tile 0 into buf 0

    for (int st = 0; st < nst; st++) {
        const int buf = st & 1;
        __builtin_amdgcn_s_barrier();            // all waves done computing st-1
        if (st + 1 < nst) {
            AST(st + 1, buf ^ 1);
            asm volatile("s_waitcnt vmcnt(4)" ::: "memory");   // st's loads landed
        } else {
            asm volatile("s_waitcnt vmcnt(0)" ::: "memory");
        }
        __builtin_amdgcn_s_barrier();            // everyone's st loads visible

        if (st <= mylast) {  // wave-uniform predicate (w-dependent)
            const ushort* Kb = &Kf[buf][0];
            const ushort* Vb = &Vf[buf][0];
            // ---- S^T = K · Q^T ----
            f32x16 S;
#pragma unroll
            for (int r = 0; r < 16; r++) S[r] = 0.f;
            __builtin_amdgcn_s_setprio(1);
#pragma unroll
            for (int kt = 0; kt < 8; kt++) {
                short8 afK = *(const short8*)(Kb + kt * 512 + l * 8);
                S = __builtin_amdgcn_mfma_f32_32x32x16_bf16(afK, qf[kt], S, 0, 0, 0);
            }
            __builtin_amdgcn_s_setprio(0);

            float p[16];
#pragma unroll
            for (int r = 0; r < 16; r++) p[r] = S[r];
            if (st == mylast) {
                const int sb = st * 32 + 4 * hf;
#pragma unroll
                for (int r = 0; r < 16; r++) {
                    const int sg = sb + (r & 3) + 8 * (r >> 2);
                    if (sg > qg) p[r] = -INFINITY;
                }
            }
            float rmax = p[0];
#pragma unroll
            for (int r = 1; r < 16; r++) rmax = fmaxf(rmax, p[r]);
            rmax = fmaxf(rmax, __shfl_xor(rmax, 32));
            const float mnew = fmaxf(mcur, rmax);
            const float alpha = __expf(mcur - mnew);
            float rsum = 0.f;
#pragma unroll
            for (int r = 0; r < 16; r++) {
                p[r] = __expf(p[r] - mnew);
                rsum += p[r];
            }
            rsum += __shfl_xor(rsum, 32);
            lcur = lcur * alpha + rsum;
            mcur = mnew;

#pragma unroll
            for (int dt = 0; dt < 4; dt++)
#pragma unroll
                for (int r = 0; r < 16; r++) O[dt][r] *= alpha;

            unsigned pk[8], rk[8];
#pragma unroll
            for (int g = 0; g < 4; g++) {
                pk[2 * g]     = (unsigned)f2bf(p[4 * g])     | ((unsigned)f2bf(p[4 * g + 1]) << 16);
                pk[2 * g + 1] = (unsigned)f2bf(p[4 * g + 2]) | ((unsigned)f2bf(p[4 * g + 3]) << 16);
            }
#pragma unroll
            for (int i = 0; i < 8; i++) rk[i] = (unsigned)__shfl_xor((int)pk[i], 32);

            short8 Pf[2];
#pragma unroll
            for (int kt2 = 0; kt2 < 2; kt2++) {
                const int g = 2 * kt2 + hf;
                union { unsigned u[4]; short8 s; } cvt;
                cvt.u[0] = hf ? rk[2 * g]     : pk[2 * g];
                cvt.u[1] = hf ? rk[2 * g + 1] : pk[2 * g + 1];
                cvt.u[2] = hf ? pk[2 * g]     : rk[2 * g];
                cvt.u[3] = hf ? pk[2 * g + 1] : rk[2 * g + 1];
                Pf[kt2] = cvt.s;
            }

            __builtin_amdgcn_s_setprio(1);
#pragma unroll
            for (int dt = 0; dt < 4; dt++)
#pragma unroll
                for (int kt2 = 0; kt2 < 2; kt2++) {
                    short8 afV = *(const short8*)(Vb + (dt * 2 + kt2) * 512 + l * 8);
                    O[dt] = __builtin_amdgcn_mfma_f32_32x32x16_bf16(afV, Pf[kt2], O[dt], 0, 0, 0);
                }
            __builtin_amdgcn_s_setprio(0);
        }
    }
#undef AST

    const float inv = 1.0f / lcur;
    ushort* orow = attnB + (size_t)qg * HDIM + h * HD + 4 * hf;
#pragma unroll
    for (int dt = 0; dt < 4; dt++)
#pragma unroll
        for (int rg = 0; rg < 4; rg++) {
            ushort4 o;
            o.x = f2bf(O[dt][4 * rg + 0] * inv);
            o.y = f2bf(O[dt][4 * rg + 1] * inv);
            o.z = f2bf(O[dt][4 * rg + 2] * inv);
            o.w = f2bf(O[dt][4 * rg + 3] * inv);
            *(ushort4*)(orow + dt * 32 + 8 * rg) = o;
        }
}

// ---------------------------------------------------------------------------
// Fallback fp32 path — used only if workspace is too small.
// ---------------------------------------------------------------------------
__global__ __launch_bounds__(256) void rope_kernel(const int* __restrict__ pos,
                                                   float* __restrict__ qkv) {
    const int t = blockIdx.x;
    const int head = blockIdx.y * 4 + (threadIdx.x >> 6);
    const int d = threadIdx.x & 63;
    const float p = (float)pos[t];
    const float invf = exp2f(-(float)d * (19.931568569324174f / 64.0f));
    const float f = p * invf;
    const float c = cosf(f), s = sinf(f);
    float* base = qkv + (size_t)t * QKVN + head * HD;
    const float x1 = base[d];
    const float x2 = base[d + 64];
    base[d]      = x1 * c - x2 * s;
    base[d + 64] = x2 * c + x1 * s;
}

#define DOT4(acc, a, b) acc += (a).x*(b).x + (a).y*(b).y + (a).z*(b).z + (a).w*(b).w
#define FMA4(o, p, v) { (o).x += (p)*(v).x; (o).y += (p)*(v).y; (o).z += (p)*(v).z; (o).w += (p)*(v).w; }

__global__ __launch_bounds__(256, 2) void flash_attn_f32(const float* __restrict__ qkv,
                                                         float* __restrict__ out) {
    __shared__ float Qs[64 * 132];
    __shared__ float KVs[32 * 132];
    __shared__ float Ps[64 * 34];
    const int b = blockIdx.x;
    const int half = (b >> 9) & 1;
    const int rest = b & 511;
    const int h = rest >> 4;
    const int qlo = rest & 15;
    const int qi = half ? (31 - qlo) : qlo;
    const int kvh = h >> 2;
    const int tid = threadIdx.x;
    const int tx = tid & 7;
    const int ty = tid >> 3;
    {
        const float* qbase = qkv + (size_t)(qi * 64) * QKVN + h * HD;
#pragma unroll
        for (int r = 0; r < 8; r++) {
            int idx = r * 256 + tid;
            int qrow = idx >> 5;
            int d = (idx & 31) * 4;
            float4 v = *(const float4*)(qbase + (size_t)qrow * QKVN + d);
            v.x *= SCALE; v.y *= SCALE; v.z *= SCALE; v.w *= SCALE;
            *(float4*)(Qs + qrow * 132 + d) = v;
        }
    }
    float m[2], lsm[2];
    float4 O[2][4];
#pragma unroll
    for (int i = 0; i < 2; i++) {
        m[i] = -INFINITY; lsm[i] = 0.f;
#pragma unroll
        for (int jj = 0; jj < 4; jj++) O[i][jj] = make_float4(0.f, 0.f, 0.f, 0.f);
    }
    const float* kbase = qkv + KV_OFF + kvh * HD;
    const float* vbase = qkv + V_OFF + kvh * HD;
    const int qg0 = qi * 64 + ty;
    const int nst = 2 * qi + 2;
    for (int st = 0; st < nst; st++) {
        __syncthreads();
#pragma unroll
        for (int r = 0; r < 4; r++) {
            int idx = r * 256 + tid;
            int srow = idx >> 5;
            int d = (idx & 31) * 4;
            *(float4*)(KVs + srow * 132 + d) =
                *(const float4*)(kbase + (size_t)(st * 32 + srow) * QKVN + d);
        }
        __syncthreads();
        float S[2][4];
#pragma unroll
        for (int i = 0; i < 2; i++)
#pragma unroll
            for (int j = 0; j < 4; j++) S[i][j] = 0.f;
#pragma unroll 4
        for (int kk = 0; kk < HD; kk += 4) {
            float4 q0 = *(const float4*)(Qs + ty * 132 + kk);
            float4 q1 = *(const float4*)(Qs + (ty + 32) * 132 + kk);
            float4 k0 = *(const float4*)(KVs + tx * 132 + kk);
            float4 k1 = *(const float4*)(KVs + (tx + 8) * 132 + kk);
            float4 k2 = *(const float4*)(KVs + (tx + 16) * 132 + kk);
            float4 k3 = *(const float4*)(KVs + (tx + 24) * 132 + kk);
            DOT4(S[0][0], q0, k0); DOT4(S[0][1], q0, k1);
            DOT4(S[0][2], q0, k2); DOT4(S[0][3], q0, k3);
            DOT4(S[1][0], q1, k0); DOT4(S[1][1], q1, k1);
            DOT4(S[1][2], q1, k2); DOT4(S[1][3], q1, k3);
        }
        const int sg0 = st * 32 + tx;
        float alpha[2];
#pragma unroll
        for (int i = 0; i < 2; i++) {
            const int qg = qg0 + 32 * i;
            float rmax = -INFINITY;
#pragma unroll
            for (int j = 0; j < 4; j++) {
                if (sg0 + 8 * j > qg) S[i][j] = -INFINITY;
                rmax = fmaxf(rmax, S[i][j]);
            }
#pragma unroll
            for (int off = 1; off < 8; off <<= 1)
                rmax = fmaxf(rmax, __shfl_xor(rmax, off));
            const float mnew = fmaxf(m[i], rmax);
            alpha[i] = __expf(m[i] - mnew);
            float rsum = 0.f;
#pragma unroll
            for (int j = 0; j < 4; j++) {
                S[i][j] = __expf(S[i][j] - mnew);
                rsum += S[i][j];
            }
#pragma unroll
            for (int off = 1; off < 8; off <<= 1)
                rsum += __shfl_xor(rsum, off);
            lsm[i] = lsm[i] * alpha[i] + rsum;
            m[i] = mnew;
        }
#pragma unroll
        for (int i = 0; i < 2; i++)
#pragma unroll
            for (int j = 0; j < 4; j++)
                Ps[(ty + 32 * i) * 34 + tx + 8 * j] = S[i][j];
        __syncthreads();
#pragma unroll
        for (int r = 0; r < 4; r++) {
            int idx = r * 256 + tid;
            int srow = idx >> 5;
            int d = (idx & 31) * 4;
            *(float4*)(KVs + srow * 132 + d) =
                *(const float4*)(vbase + (size_t)(st * 32 + srow) * QKVN + d);
        }
        __syncthreads();
#pragma unroll
        for (int i = 0; i < 2; i++) {
            const float a = alpha[i];
#pragma unroll
            for (int jj = 0; jj < 4; jj++) {
                O[i][jj].x *= a; O[i][jj].y *= a; O[i][jj].z *= a; O[i][jj].w *= a;
            }
        }
#pragma unroll 4
        for (int s = 0; s < 32; s++) {
            float p0 = Ps[ty * 34 + s];
            float p1 = Ps[(ty + 32) * 34 + s];
            const float* vr = KVs + s * 132 + 4 * tx;
            float4 v0 = *(const float4*)(vr);
            float4 v1 = *(const float4*)(vr + 32);
            float4 v2 = *(const float4*)(vr + 64);
            float4 v3 = *(const float4*)(vr + 96);
            FMA4(O[0][0], p0, v0); FMA4(O[0][1], p0, v1);
            FMA4(O[0][2], p0, v2); FMA4(O[0][3], p0, v3);
            FMA4(O[1][0], p1, v0); FMA4(O[1][1], p1, v1);
            FMA4(O[1][2], p1, v2); FMA4(O[1][3], p1, v3);
        }
    }
#pragma unroll
    for (int i = 0; i < 2; i++) {
        const float inv = 1.0f / lsm[i];
        float* orow = out + (size_t)(qi * 64 + ty + 32 * i) * HDIM + h * HD + 4 * tx;
#pragma unroll
        for (int jj = 0; jj < 4; jj++) {
            float4 wv = O[i][jj];
            wv.x *= inv; wv.y *= inv; wv.z *= inv; wv.w *= inv;
            *(float4*)(orow + 32 * jj) = wv;
        }
    }
}

template <int N_, int K_>
__global__ __launch_bounds__(256) void sgemm(const float* __restrict__ A,
                                             const float* __restrict__ B,
                                             float* __restrict__ C) {
    __shared__ float As[8][128];
    __shared__ float Bs[8][128];
    const int tid = threadIdx.x;
    const int bm = blockIdx.y * 128;
    const int bn = blockIdx.x * 128;
    const int tx = tid & 15;
    const int ty = tid >> 4;
    const int lm = tid >> 1;
    const int lkq = (tid & 1) * 4;
    const int lr = tid >> 5;
    const int lnq = (tid & 31) * 4;
    float acc[8][8];
#pragma unroll
    for (int i = 0; i < 8; i++)
#pragma unroll
        for (int j = 0; j < 8; j++) acc[i][j] = 0.f;
    const float* Aptr = A + (size_t)(bm + lm) * K_ + lkq;
    const float* Bptr = B + (size_t)lr * N_ + bn + lnq;
    for (int k0 = 0; k0 < K_; k0 += 8) {
        float4 av = *(const float4*)Aptr;
        float4 bv = *(const float4*)Bptr;
        __syncthreads();
        As[lkq + 0][lm] = av.x;
        As[lkq + 1][lm] = av.y;
        As[lkq + 2][lm] = av.z;
        As[lkq + 3][lm] = av.w;
        *(float4*)&Bs[lr][lnq] = bv;
        __syncthreads();
        Aptr += 8;
        Bptr += (size_t)8 * N_;
#pragma unroll
        for (int kk = 0; kk < 8; kk++) {
            float4 a0 = *(const float4*)&As[kk][ty * 4];
            float4 a1 = *(const float4*)&As[kk][64 + ty * 4];
            float4 b0 = *(const float4*)&Bs[kk][tx * 4];
            float4 b1 = *(const float4*)&Bs[kk][64 + tx * 4];
            float a[8] = {a0.x, a0.y, a0.z, a0.w, a1.x, a1.y, a1.z, a1.w};
            float bb[8] = {b0.x, b0.y, b0.z, b0.w, b1.x, b1.y, b1.z, b1.w};
#pragma unroll
            for (int i = 0; i < 8; i++)
#pragma unroll
                for (int j = 0; j < 8; j++) acc[i][j] += a[i] * bb[j];
        }
    }
#pragma unroll
    for (int i = 0; i < 8; i++) {
        int row = bm + ((i < 4) ? (ty * 4 + i) : (64 + ty * 4 + i - 4));
        float4 c0 = {acc[i][0], acc[i][1], acc[i][2], acc[i][3]};
        float4 c1 = {acc[i][4], acc[i][5], acc[i][6], acc[i][7]};
        *(float4*)&C[(size_t)row * N_ + bn + tx * 4] = c0;
        *(float4*)&C[(size_t)row * N_ + bn + 64 + tx * 4] = c1;
    }
}

// ---------------------------------------------------------------------------
extern "C" void kernel_launch(void* const* d_in, const int* in_sizes, int n_in,
                              void* d_out, int out_size, void* d_ws, size_t ws_size,
                              hipStream_t stream) {
    const int*   positions = (const int*)d_in[0];
    const float* hidden    = (const float*)d_in[1];
    const float* Wqkv      = (const float*)d_in[2];
    const float* Wo        = (const float*)d_in[3];
    float* out = (float*)d_out;

    char* ws = (char*)d_ws;
    float*  qkv   = (float*)ws;                     // [0, 50331648)
    ushort* attnB = (ushort*)ws;                    // overlays dead qkv [0, 16777216)
    float*  Pk    = (float*)(ws + 16777216);        // split-K partial [16777216, 50331648)
    ushort* WqkvT = (ushort*)(ws + 50331648);       // 50331648
    ushort* WoT   = (ushort*)(ws + 100663296);      // 33554432
    ushort* hA    = (ushort*)(ws + 134217728);      // 16777216 (dead after gemm1)
    ushort* qkB   = (ushort*)(ws + 134217728);      // 25165824 overlays hA
    ushort* Vt    = (ushort*)(ws + 159383552);      // 4194304
    const size_t NEEDED = 163577856;

    if (ws_size >= NEEDED) {
        cast_bf16<<<dim3((T_TOK * HDIM) / 1024), 256, 0, stream>>>(hidden, hA);
        transpose_cast<HDIM, QKVN><<<dim3(QKVN / 64, HDIM / 32), 256, 0, stream>>>(Wqkv, WqkvT);
        transpose_cast<HDIM, HDIM><<<dim3(HDIM / 64, HDIM / 32), 256, 0, stream>>>(Wo, WoT);
        gemm_bf16_8ph<QKVN, HDIM, HDIM>
            <<<dim3((T_TOK / 256) * (QKVN / 256), 1), 512, 0, stream>>>(hA, WqkvT, qkv, qkv);
        rope_cast<<<dim3(T_TOK, 10), 256, 0, stream>>>(positions, qkv, qkB);
        vt_cast<<<dim3(T_TOK / 32, 32), 256, 0, stream>>>(qkv, Vt);
        flash_attn_mfma<<<dim3(512), 256, 0, stream>>>(qkB, Vt, attnB);
        gemm_bf16_8ph<HDIM, HDIM, HDIM / 2>
            <<<dim3((T_TOK / 256) * (HDIM / 256), 2), 512, 0, stream>>>(attnB, WoT, out, Pk);
        add_f32<<<dim3((T_TOK * HDIM) / 1024), 256, 0, stream>>>(out, Pk);
    } else {
        float* attn = qkv + (size_t)T_TOK * QKVN;
        sgemm<QKVN, HDIM><<<dim3(QKVN / 128, T_TOK / 128), 256, 0, stream>>>(hidden, Wqkv, qkv);
        rope_kernel<<<dim3(T_TOK, 10), 256, 0, stream>>>(positions, qkv);
        flash_attn_f32<<<dim3(1024), 256, 0, stream>>>(qkv, attn);
        sgemm<HDIM, HDIM><<<dim3(HDIM / 128, T_TOK / 128), 256, 0, stream>>>(attn, Wo, out);
    }
}

// Round 3
// 650.144 us; speedup vs baseline: 1.1328x; 1.1328x over previous
//
#include <hip/hip_runtime.h>
#include <math.h>

#define T_TOK 2048
#define HDIM  4096
#define QKVN  6144
#define NHEADS 32
#define HD    128
#define KV_OFF 4096
#define V_OFF  5120
#define SCALE 0.08838834764831843f

typedef __attribute__((ext_vector_type(8))) short short8;
typedef __attribute__((ext_vector_type(4))) float f32x4;
typedef __attribute__((ext_vector_type(16))) float f32x16;

__device__ __forceinline__ ushort f2bf(float f) {
    union { float f; unsigned u; } v; v.f = f;
    unsigned r = v.u + 0x7FFFu + ((v.u >> 16) & 1u);   // RNE
    return (ushort)(r >> 16);
}

// ---------------------------------------------------------------------------
// 256x256 8-phase bf16 MFMA GEMM, C[M,N] = A[M,:]*B^T[N,:], row stride LDK,
// K-extent KC (split-K via blockIdx.y; kz=0 -> C0, kz=1 -> C1).
// 8 waves (2M x 4N), BK=64, double-buffered LDS (128 KiB).
// R3 schedule (m201-faithful): reads issue at TOP of phase and are consumed
// by the SAME phase's MFMA after {barrier; lgkmcnt(0)}. No end-of-phase LDS
// drain (R2's mistake). Read distribution 12/4/8/0. Single-copy operand regs
// (a0/aH/b01/b23) keep VGPR at ~116 + 128 acc.
// WAR-safe: each stage overwriting slot S is issued after the barrier that
// postdates the lgkm-complete of S's last ds_read.
// ---------------------------------------------------------------------------
template <int N_, int LDK, int KC>
__global__ __launch_bounds__(512, 2) void gemm_bf16_8ph(const ushort* __restrict__ A,
                                                        const ushort* __restrict__ B,
                                                        float* __restrict__ C0,
                                                        float* __restrict__ C1) {
    __shared__ __attribute__((aligned(16))) ushort As[2][2][8192];  // [buf][half][128*64]
    __shared__ __attribute__((aligned(16))) ushort Bs[2][2][8192];

    constexpr int NT = KC / 64;
    constexpr int NBN = N_ / 256;

    const int kz = blockIdx.y;
    float* __restrict__ C = kz ? C1 : C0;

    const int nwgx = (int)gridDim.x;
    const int bid = (int)blockIdx.x;
    const int swz = (nwgx & 7) ? bid : ((bid & 7) * (nwgx >> 3) + (bid >> 3));  // XCD swizzle
    const int bm = (swz / NBN) * 256;
    const int bn = (swz % NBN) * 256;

    const int tid = (int)threadIdx.x;
    const int w = tid >> 6;           // 0..7
    const int l = tid & 63;
    const int hfa = w >> 2;           // A half used by this wave
    const int hfb = (w & 3) >> 1;     // B half used by this wave
    const int wbr64 = (w & 1) * 4096; // row-offset*64 within B half

    // ds-read addressing: element idx = frag*1024 + (l&15)*64 + colswz
    const int arc = (l & 15) * 64;
    const int ac0 = ((((l >> 4) << 4)) ^ ((l & 7) << 4)) >> 1;
    const int ac1 = (((1 << 6) | ((l >> 4) << 4)) ^ ((l & 7) << 4)) >> 1;

    // stage source addressing (inverse swizzle folded into per-lane col)
    const int grow = w * 8 + (l >> 3);            // 0..63
    const int gcol = ((l & 7) ^ (l >> 3)) * 8;    // element col within 64
    const ushort* Ag = A + (size_t)kz * KC + (size_t)(bm + grow) * LDK + gcol;
    const ushort* Bg = B + (size_t)kz * KC + (size_t)(bn + grow) * LDK + gcol;

    auto ldsA = (__attribute__((address_space(3))) char*)&As[0][0][0];
    auto ldsB = (__attribute__((address_space(3))) char*)&Bs[0][0][0];
    const int wsl = w * 1024;

#define STG2(ldsbase, gsrc, bufi, hfi, kt)                                                              \
    do {                                                                                                \
        __builtin_amdgcn_global_load_lds(                                                               \
            (const __attribute__((address_space(1))) void*)((gsrc) + (size_t)((hfi) * 128) * LDK + (kt) * 64),       \
            (__attribute__((address_space(3))) void*)((ldsbase) + (bufi) * 32768 + (hfi) * 16384 + wsl), 16, 0, 0);  \
        __builtin_amdgcn_global_load_lds(                                                               \
            (const __attribute__((address_space(1))) void*)((gsrc) + (size_t)((hfi) * 128 + 64) * LDK + (kt) * 64),  \
            (__attribute__((address_space(3))) void*)((ldsbase) + (bufi) * 32768 + (hfi) * 16384 + 8192 + wsl), 16, 0, 0); \
    } while (0)

    // prologue: tile0 fully, then tile1 (B-h0,B-h1,A-h0)
    STG2(ldsB, Bg, 0, 0, 0);
    STG2(ldsB, Bg, 0, 1, 0);
    STG2(ldsA, Ag, 0, 0, 0);
    STG2(ldsA, Ag, 0, 1, 0);
    STG2(ldsB, Bg, 1, 0, 1);
    STG2(ldsB, Bg, 1, 1, 1);
    STG2(ldsA, Ag, 1, 0, 1);
    asm volatile("s_waitcnt vmcnt(6)" ::: "memory");   // tile0's 8 loads done
    __builtin_amdgcn_s_barrier();

    f32x4 acc[8][4];
#pragma unroll
    for (int i = 0; i < 8; i++)
#pragma unroll
        for (int j = 0; j < 4; j++) acc[i][j] = (f32x4){0.f, 0.f, 0.f, 0.f};

    short8 a0[4][2], aH[4][2], b01[2][2], b23[2][2];

    int buf = 0;
    for (int t = 0; t < NT; ++t) {
        const int nb = buf ^ 1;
        const ushort* Abuf = &As[buf][hfa][0];
        const ushort* Bbuf = &Bs[buf][hfb][0] + wbr64;

        // ---- phase 1: read a0(8)+b01(4); stage A-h1(t+1); MFMA acc[0..3][0..1] ----
#pragma unroll
        for (int fi = 0; fi < 4; fi++) {
            a0[fi][0] = *(const short8*)(Abuf + fi * 1024 + arc + ac0);
            a0[fi][1] = *(const short8*)(Abuf + fi * 1024 + arc + ac1);
        }
#pragma unroll
        for (int fj = 0; fj < 2; fj++) {
            b01[fj][0] = *(const short8*)(Bbuf + fj * 1024 + arc + ac0);
            b01[fj][1] = *(const short8*)(Bbuf + fj * 1024 + arc + ac1);
        }
        if (t + 1 < NT) STG2(ldsA, Ag, nb, 1, t + 1);
        asm volatile("s_waitcnt lgkmcnt(8)" ::: "memory");
        __builtin_amdgcn_s_barrier();
        asm volatile("s_waitcnt lgkmcnt(0)" ::: "memory");
        __builtin_amdgcn_s_setprio(1);
#pragma unroll
        for (int fi = 0; fi < 4; fi++)
#pragma unroll
            for (int fj = 0; fj < 2; fj++)
#pragma unroll
                for (int s = 0; s < 2; s++)
                    acc[fi][fj] = __builtin_amdgcn_mfma_f32_16x16x32_bf16(a0[fi][s], b01[fj][s], acc[fi][fj], 0, 0, 0);
        __builtin_amdgcn_s_setprio(0);
        __builtin_amdgcn_s_barrier();

        // ---- phase 2: read b23(4); stage B-h0(t+2); MFMA acc[0..3][2..3] ----
#pragma unroll
        for (int fj = 0; fj < 2; fj++) {
            b23[fj][0] = *(const short8*)(Bbuf + (fj + 2) * 1024 + arc + ac0);
            b23[fj][1] = *(const short8*)(Bbuf + (fj + 2) * 1024 + arc + ac1);
        }
        if (t + 2 < NT) STG2(ldsB, Bg, buf, 0, t + 2);
        __builtin_amdgcn_s_barrier();
        asm volatile("s_waitcnt lgkmcnt(0)" ::: "memory");
        __builtin_amdgcn_s_setprio(1);
#pragma unroll
        for (int fi = 0; fi < 4; fi++)
#pragma unroll
            for (int fj = 0; fj < 2; fj++)
#pragma unroll
                for (int s = 0; s < 2; s++)
                    acc[fi][fj + 2] = __builtin_amdgcn_mfma_f32_16x16x32_bf16(a0[fi][s], b23[fj][s], acc[fi][fj + 2], 0, 0, 0);
        __builtin_amdgcn_s_setprio(0);
        __builtin_amdgcn_s_barrier();

        // ---- phase 3: read aH(8); stage B-h1(t+2); MFMA acc[4..7][2..3] ----
#pragma unroll
        for (int fi = 0; fi < 4; fi++) {
            aH[fi][0] = *(const short8*)(Abuf + (fi + 4) * 1024 + arc + ac0);
            aH[fi][1] = *(const short8*)(Abuf + (fi + 4) * 1024 + arc + ac1);
        }
        if (t + 2 < NT) STG2(ldsB, Bg, buf, 1, t + 2);
        __builtin_amdgcn_s_barrier();
        asm volatile("s_waitcnt lgkmcnt(0)" ::: "memory");
        __builtin_amdgcn_s_setprio(1);
#pragma unroll
        for (int fi = 0; fi < 4; fi++)
#pragma unroll
            for (int fj = 0; fj < 2; fj++)
#pragma unroll
                for (int s = 0; s < 2; s++)
                    acc[fi + 4][fj + 2] = __builtin_amdgcn_mfma_f32_16x16x32_bf16(aH[fi][s], b23[fj][s], acc[fi + 4][fj + 2], 0, 0, 0);
        __builtin_amdgcn_s_setprio(0);
        __builtin_amdgcn_s_barrier();

        // ---- phase 4: stage A-h0(t+2); vmcnt(6); MFMA acc[4..7][0..1] ----
        if (t + 2 < NT) {
            STG2(ldsA, Ag, buf, 0, t + 2);
            asm volatile("s_waitcnt vmcnt(6)" ::: "memory");   // tile t+1 fully landed
        } else {
            asm volatile("s_waitcnt vmcnt(0)" ::: "memory");   // tail drain
        }
        __builtin_amdgcn_s_barrier();
        __builtin_amdgcn_s_setprio(1);
#pragma unroll
        for (int fi = 0; fi < 4; fi++)
#pragma unroll
            for (int fj = 0; fj < 2; fj++)
#pragma unroll
                for (int s = 0; s < 2; s++)
                    acc[fi + 4][fj] = __builtin_amdgcn_mfma_f32_16x16x32_bf16(aH[fi][s], b01[fj][s], acc[fi + 4][fj], 0, 0, 0);
        __builtin_amdgcn_s_setprio(0);
        __builtin_amdgcn_s_barrier();

        buf = nb;
    }
#undef STG2

    // epilogue: C-frag layout col=l&15, row=(l>>4)*4+r
    const int cn = bn + (w & 3) * 64 + (l & 15);
    const int rm = bm + hfa * 128 + ((l >> 4) << 2);
#pragma unroll
    for (int fi = 0; fi < 8; fi++)
#pragma unroll
        for (int fj = 0; fj < 4; fj++)
#pragma unroll
            for (int r = 0; r < 4; r++)
                C[(size_t)(rm + 16 * fi + r) * N_ + cn + 16 * fj] = acc[fi][fj][r];
}

// ---------------------------------------------------------------------------
__global__ __launch_bounds__(256) void add_f32(float* __restrict__ out,
                                               const float* __restrict__ p) {
    const int i = (blockIdx.x * 256 + threadIdx.x) * 4;
    float4 a = *(const float4*)(out + i);
    float4 b = *(const float4*)(p + i);
    a.x += b.x; a.y += b.y; a.z += b.z; a.w += b.w;
    *(float4*)(out + i) = a;
}

// ---------------------------------------------------------------------------
__global__ __launch_bounds__(256) void cast_bf16(const float* __restrict__ in,
                                                 ushort* __restrict__ outp) {
    const int i = (blockIdx.x * 256 + threadIdx.x) * 4;
    float4 v = *(const float4*)(in + i);
    ushort4 o = {f2bf(v.x), f2bf(v.y), f2bf(v.z), f2bf(v.w)};
    *(ushort4*)(outp + i) = o;
}

// ---------------------------------------------------------------------------
template <int K_, int N_>
__global__ __launch_bounds__(256) void transpose_cast(const float* __restrict__ W,
                                                      ushort* __restrict__ WT) {
    __shared__ float T[32 * 65];
    const int k0 = blockIdx.y * 32;
    const int n0 = blockIdx.x * 64;
    const int x = threadIdx.x & 63;
    const int y = threadIdx.x >> 6;
#pragma unroll
    for (int p = 0; p < 8; p++) {
        const int kk = p * 4 + y;
        T[kk * 65 + x] = W[(size_t)(k0 + kk) * N_ + n0 + x];
    }
    __syncthreads();
#pragma unroll
    for (int q = 0; q < 4; q++) {
        const int nl = q * 16 + (threadIdx.x >> 4);
        const int k2 = (threadIdx.x & 15) * 2;
        ushort2 o = {f2bf(T[k2 * 65 + nl]), f2bf(T[(k2 + 1) * 65 + nl])};
        *(ushort2*)&WT[(size_t)(n0 + nl) * K_ + k0 + k2] = o;
    }
}

// ---------------------------------------------------------------------------
// NeoX RoPE fp32 qkv -> bf16 qkB for q (scaled) and k heads. v cols unwritten.
// ---------------------------------------------------------------------------
__global__ __launch_bounds__(256) void rope_cast(const int* __restrict__ pos,
                                                 const float* __restrict__ qkv,
                                                 ushort* __restrict__ qkB) {
    const int t = blockIdx.x;
    const int slot = blockIdx.y * 4 + (threadIdx.x >> 6);   // 0..39
    const int d = threadIdx.x & 63;
    const float p = (float)pos[t];
    const float invf = exp2f(-(float)d * (19.931568569324174f / 64.0f));
    const float f = p * invf;
    const float c = cosf(f), s = sinf(f);
    const float sc = (slot < 32) ? SCALE : 1.0f;
    const float* base = qkv + (size_t)t * QKVN + slot * HD;
    ushort* ob = qkB + (size_t)t * QKVN + slot * HD;
    const float x1 = base[d];
    const float x2 = base[d + 64];
    ob[d]      = f2bf((x1 * c - x2 * s) * sc);
    ob[d + 64] = f2bf((x2 * c + x1 * s) * sc);
}

// ---------------------------------------------------------------------------
// V transpose: qkv fp32 v-part [t][5120 + c] -> Vt bf16 [c][t], c = kvh*128+d.
// ---------------------------------------------------------------------------
__global__ __launch_bounds__(256) void vt_cast(const float* __restrict__ qkv,
                                               ushort* __restrict__ Vt) {
    __shared__ float tile[32][33];
    const int t0 = blockIdx.x * 32;
    const int c0 = blockIdx.y * 32;
    const int tx = threadIdx.x & 31;
    const int ty = threadIdx.x >> 5;   // 0..7
#pragma unroll
    for (int i = 0; i < 4; i++) {
        const int tt = ty + 8 * i;
        tile[tt][tx] = qkv[(size_t)(t0 + tt) * QKVN + V_OFF + c0 + tx];
    }
    __syncthreads();
#pragma unroll
    for (int i = 0; i < 4; i++) {
        const int dd = ty + 8 * i;
        Vt[(size_t)(c0 + dd) * 2048 + t0 + tx] = f2bf(tile[tx][dd]);
    }
}

// ---------------------------------------------------------------------------
// MFMA flash attention, double-buffered staging (raw s_barrier + vmcnt(4)):
// each tile's 4 global_load_lds have a full compute phase to land.
// ---------------------------------------------------------------------------
__global__ __launch_bounds__(256, 2) void flash_attn_mfma(
        const ushort* __restrict__ qkB,
        const ushort* __restrict__ Vt,
        ushort* __restrict__ attnB) {
    __shared__ ushort Kf[2][8 * 512];   // [buf][8 frags x 1024 B]
    __shared__ ushort Vf[2][8 * 512];

    const int b = blockIdx.x;              // 512
    const int half = b >> 8;
    const int rest = b & 255;
    const int h = rest >> 3;               // 0..31
    const int q8 = rest & 7;
    const int qi = half ? (15 - q8) : q8;  // 0..15, paired for balance
    const int kvh = h >> 2;

    const int tid = threadIdx.x;
    const int w = tid >> 6;
    const int l = tid & 63;
    const int l31 = l & 31;
    const int hf = l >> 5;

    const int qg = qi * 128 + w * 32 + l31;   // this lane's q row

    short8 qf[8];
    {
        const ushort* qrow = qkB + (size_t)qg * QKVN + h * HD + hf * 8;
#pragma unroll
        for (int kt = 0; kt < 8; kt++)
            qf[kt] = *(const short8*)(qrow + kt * 16);
    }

    f32x16 O[4];
#pragma unroll
    for (int dt = 0; dt < 4; dt++)
#pragma unroll
        for (int r = 0; r < 16; r++) O[dt][r] = 0.f;
    float mcur = -INFINITY, lcur = 0.f;

    const ushort* kbase = qkB + (size_t)l31 * QKVN + KV_OFF + kvh * HD + (2 * w) * 16 + hf * 8;
    const ushort* vbase = Vt + ((size_t)(kvh * 128 + w * 32 + l31)) * 2048 + hf * 8;

    auto ldsK = (__attribute__((address_space(3))) char*)&Kf[0][0];
    auto ldsV = (__attribute__((address_space(3))) char*)&Vf[0][0];

    const int nst = 4 * qi + 4;
    const int mylast = 4 * qi + w;

#define AST(s, bb)                                                                               \
    do {                                                                                         \
        const ushort* kg = kbase + (size_t)(s) * 32 * QKVN;                                      \
        __builtin_amdgcn_global_load_lds(                                                        \
            (const __attribute__((address_space(1))) void*)kg,                                   \
            (__attribute__((address_space(3))) void*)(ldsK + (bb) * 8192 + (2 * w) * 1024), 16, 0, 0);      \
        __builtin_amdgcn_global_load_lds(                                                        \
            (const __attribute__((address_space(1))) void*)(kg + 16),                            \
            (__attribute__((address_space(3))) void*)(ldsK + (bb) * 8192 + (2 * w + 1) * 1024), 16, 0, 0);  \
        const ushort* vg = vbase + (s) * 32;                                                     \
        __builtin_amdgcn_global_load_lds(                                                        \
            (const __attribute__((address_space(1))) void*)vg,                                   \
            (__attribute__((address_space(3))) void*)(ldsV + (bb) * 8192 + (2 * w) * 1024), 16, 0, 0);      \
        __builtin_amdgcn_global_load_lds(                                                        \
            (const __attribute__((address_space(1))) void*)(vg + 16),                            \
            (__attribute__((address_space(3))) void*)(ldsV + (bb) * 8192 + (2 * w + 1) * 1024), 16, 0, 0);  \
    } while (0)

    AST(0, 0);   // prologue: stage tile 0 into buf 0

    for (int st = 0; st < nst; st++) {
        const int buf = st & 1;
        __builtin_amdgcn_s_barrier();            // all waves done computing st-1
        if (st + 1 < nst) {
            AST(st + 1, buf ^ 1);
            asm volatile("s_waitcnt vmcnt(4)" ::: "memory");   // st's loads landed
        } else {
            asm volatile("s_waitcnt vmcnt(0)" ::: "memory");
        }
        __builtin_amdgcn_s_barrier();            // everyone's st loads visible

        if (st <= mylast) {  // wave-uniform predicate (w-dependent)
            const ushort* Kb = &Kf[buf][0];
            const ushort* Vb = &Vf[buf][0];
            // ---- S^T = K · Q^T ----
            f32x16 S;
#pragma unroll
            for (int r = 0; r < 16; r++) S[r] = 0.f;
            __builtin_amdgcn_s_setprio(1);
#pragma unroll
            for (int kt = 0; kt < 8; kt++) {
                short8 afK = *(const short8*)(Kb + kt * 512 + l * 8);
                S = __builtin_amdgcn_mfma_f32_32x32x16_bf16(afK, qf[kt], S, 0, 0, 0);
            }
            __builtin_amdgcn_s_setprio(0);

            float p[16];
#pragma unroll
            for (int r = 0; r < 16; r++) p[r] = S[r];
            if (st == mylast) {
                const int sb = st * 32 + 4 * hf;
#pragma unroll
                for (int r = 0; r < 16; r++) {
                    const int sg = sb + (r & 3) + 8 * (r >> 2);
                    if (sg > qg) p[r] = -INFINITY;
                }
            }
            float rmax = p[0];
#pragma unroll
            for (int r = 1; r < 16; r++) rmax = fmaxf(rmax, p[r]);
            rmax = fmaxf(rmax, __shfl_xor(rmax, 32));
            const float mnew = fmaxf(mcur, rmax);
            const float alpha = __expf(mcur - mnew);
            float rsum = 0.f;
#pragma unroll
            for (int r = 0; r < 16; r++) {
                p[r] = __expf(p[r] - mnew);
                rsum += p[r];
            }
            rsum += __shfl_xor(rsum, 32);
            lcur = lcur * alpha + rsum;
            mcur = mnew;

#pragma unroll
            for (int dt = 0; dt < 4; dt++)
#pragma unroll
                for (int r = 0; r < 16; r++) O[dt][r] *= alpha;

            unsigned pk[8], rk[8];
#pragma unroll
            for (int g = 0; g < 4; g++) {
                pk[2 * g]     = (unsigned)f2bf(p[4 * g])     | ((unsigned)f2bf(p[4 * g + 1]) << 16);
                pk[2 * g + 1] = (unsigned)f2bf(p[4 * g + 2]) | ((unsigned)f2bf(p[4 * g + 3]) << 16);
            }
#pragma unroll
            for (int i = 0; i < 8; i++) rk[i] = (unsigned)__shfl_xor((int)pk[i], 32);

            short8 Pf[2];
#pragma unroll
            for (int kt2 = 0; kt2 < 2; kt2++) {
                const int g = 2 * kt2 + hf;
                union { unsigned u[4]; short8 s; } cvt;
                cvt.u[0] = hf ? rk[2 * g]     : pk[2 * g];
                cvt.u[1] = hf ? rk[2 * g + 1] : pk[2 * g + 1];
                cvt.u[2] = hf ? pk[2 * g]     : rk[2 * g];
                cvt.u[3] = hf ? pk[2 * g + 1] : rk[2 * g + 1];
                Pf[kt2] = cvt.s;
            }

            __builtin_amdgcn_s_setprio(1);
#pragma unroll
            for (int dt = 0; dt < 4; dt++)
#pragma unroll
                for (int kt2 = 0; kt2 < 2; kt2++) {
                    short8 afV = *(const short8*)(Vb + (dt * 2 + kt2) * 512 + l * 8);
                    O[dt] = __builtin_amdgcn_mfma_f32_32x32x16_bf16(afV, Pf[kt2], O[dt], 0, 0, 0);
                }
            __builtin_amdgcn_s_setprio(0);
        }
    }
#undef AST

    const float inv = 1.0f / lcur;
    ushort* orow = attnB + (size_t)qg * HDIM + h * HD + 4 * hf;
#pragma unroll
    for (int dt = 0; dt < 4; dt++)
#pragma unroll
        for (int rg = 0; rg < 4; rg++) {
            ushort4 o;
            o.x = f2bf(O[dt][4 * rg + 0] * inv);
            o.y = f2bf(O[dt][4 * rg + 1] * inv);
            o.z = f2bf(O[dt][4 * rg + 2] * inv);
            o.w = f2bf(O[dt][4 * rg + 3] * inv);
            *(ushort4*)(orow + dt * 32 + 8 * rg) = o;
        }
}

// ---------------------------------------------------------------------------
// Fallback fp32 path — used only if workspace is too small.
// ---------------------------------------------------------------------------
__global__ __launch_bounds__(256) void rope_kernel(const int* __restrict__ pos,
                                                   float* __restrict__ qkv) {
    const int t = blockIdx.x;
    const int head = blockIdx.y * 4 + (threadIdx.x >> 6);
    const int d = threadIdx.x & 63;
    const float p = (float)pos[t];
    const float invf = exp2f(-(float)d * (19.931568569324174f / 64.0f));
    const float f = p * invf;
    const float c = cosf(f), s = sinf(f);
    float* base = qkv + (size_t)t * QKVN + head * HD;
    const float x1 = base[d];
    const float x2 = base[d + 64];
    base[d]      = x1 * c - x2 * s;
    base[d + 64] = x2 * c + x1 * s;
}

#define DOT4(acc, a, b) acc += (a).x*(b).x + (a).y*(b).y + (a).z*(b).z + (a).w*(b).w
#define FMA4(o, p, v) { (o).x += (p)*(v).x; (o).y += (p)*(v).y; (o).z += (p)*(v).z; (o).w += (p)*(v).w; }

__global__ __launch_bounds__(256, 2) void flash_attn_f32(const float* __restrict__ qkv,
                                                         float* __restrict__ out) {
    __shared__ float Qs[64 * 132];
    __shared__ float KVs[32 * 132];
    __shared__ float Ps[64 * 34];
    const int b = blockIdx.x;
    const int half = (b >> 9) & 1;
    const int rest = b & 511;
    const int h = rest >> 4;
    const int qlo = rest & 15;
    const int qi = half ? (31 - qlo) : qlo;
    const int kvh = h >> 2;
    const int tid = threadIdx.x;
    const int tx = tid & 7;
    const int ty = tid >> 3;
    {
        const float* qbase = qkv + (size_t)(qi * 64) * QKVN + h * HD;
#pragma unroll
        for (int r = 0; r < 8; r++) {
            int idx = r * 256 + tid;
            int qrow = idx >> 5;
            int d = (idx & 31) * 4;
            float4 v = *(const float4*)(qbase + (size_t)qrow * QKVN + d);
            v.x *= SCALE; v.y *= SCALE; v.z *= SCALE; v.w *= SCALE;
            *(float4*)(Qs + qrow * 132 + d) = v;
        }
    }
    float m[2], lsm[2];
    float4 O[2][4];
#pragma unroll
    for (int i = 0; i < 2; i++) {
        m[i] = -INFINITY; lsm[i] = 0.f;
#pragma unroll
        for (int jj = 0; jj < 4; jj++) O[i][jj] = make_float4(0.f, 0.f, 0.f, 0.f);
    }
    const float* kbase = qkv + KV_OFF + kvh * HD;
    const float* vbase = qkv + V_OFF + kvh * HD;
    const int qg0 = qi * 64 + ty;
    const int nst = 2 * qi + 2;
    for (int st = 0; st < nst; st++) {
        __syncthreads();
#pragma unroll
        for (int r = 0; r < 4; r++) {
            int idx = r * 256 + tid;
            int srow = idx >> 5;
            int d = (idx & 31) * 4;
            *(float4*)(KVs + srow * 132 + d) =
                *(const float4*)(kbase + (size_t)(st * 32 + srow) * QKVN + d);
        }
        __syncthreads();
        float S[2][4];
#pragma unroll
        for (int i = 0; i < 2; i++)
#pragma unroll
            for (int j = 0; j < 4; j++) S[i][j] = 0.f;
#pragma unroll 4
        for (int kk = 0; kk < HD; kk += 4) {
            float4 q0 = *(const float4*)(Qs + ty * 132 + kk);
            float4 q1 = *(const float4*)(Qs + (ty + 32) * 132 + kk);
            float4 k0 = *(const float4*)(KVs + tx * 132 + kk);
            float4 k1 = *(const float4*)(KVs + (tx + 8) * 132 + kk);
            float4 k2 = *(const float4*)(KVs + (tx + 16) * 132 + kk);
            float4 k3 = *(const float4*)(KVs + (tx + 24) * 132 + kk);
            DOT4(S[0][0], q0, k0); DOT4(S[0][1], q0, k1);
            DOT4(S[0][2], q0, k2); DOT4(S[0][3], q0, k3);
            DOT4(S[1][0], q1, k0); DOT4(S[1][1], q1, k1);
            DOT4(S[1][2], q1, k2); DOT4(S[1][3], q1, k3);
        }
        const int sg0 = st * 32 + tx;
        float alpha[2];
#pragma unroll
        for (int i = 0; i < 2; i++) {
            const int qg = qg0 + 32 * i;
            float rmax = -INFINITY;
#pragma unroll
            for (int j = 0; j < 4; j++) {
                if (sg0 + 8 * j > qg) S[i][j] = -INFINITY;
                rmax = fmaxf(rmax, S[i][j]);
            }
#pragma unroll
            for (int off = 1; off < 8; off <<= 1)
                rmax = fmaxf(rmax, __shfl_xor(rmax, off));
            const float mnew = fmaxf(m[i], rmax);
            alpha[i] = __expf(m[i] - mnew);
            float rsum = 0.f;
#pragma unroll
            for (int j = 0; j < 4; j++) {
                S[i][j] = __expf(S[i][j] - mnew);
                rsum += S[i][j];
            }
#pragma unroll
            for (int off = 1; off < 8; off <<= 1)
                rsum += __shfl_xor(rsum, off);
            lsm[i] = lsm[i] * alpha[i] + rsum;
            m[i] = mnew;
        }
#pragma unroll
        for (int i = 0; i < 2; i++)
#pragma unroll
            for (int j = 0; j < 4; j++)
                Ps[(ty + 32 * i) * 34 + tx + 8 * j] = S[i][j];
        __syncthreads();
#pragma unroll
        for (int r = 0; r < 4; r++) {
            int idx = r * 256 + tid;
            int srow = idx >> 5;
            int d = (idx & 31) * 4;
            *(float4*)(KVs + srow * 132 + d) =
                *(const float4*)(vbase + (size_t)(st * 32 + srow) * QKVN + d);
        }
        __syncthreads();
#pragma unroll
        for (int i = 0; i < 2; i++) {
            const float a = alpha[i];
#pragma unroll
            for (int jj = 0; jj < 4; jj++) {
                O[i][jj].x *= a; O[i][jj].y *= a; O[i][jj].z *= a; O[i][jj].w *= a;
            }
        }
#pragma unroll 4
        for (int s = 0; s < 32; s++) {
            float p0 = Ps[ty * 34 + s];
            float p1 = Ps[(ty + 32) * 34 + s];
            const float* vr = KVs + s * 132 + 4 * tx;
            float4 v0 = *(const float4*)(vr);
            float4 v1 = *(const float4*)(vr + 32);
            float4 v2 = *(const float4*)(vr + 64);
            float4 v3 = *(const float4*)(vr + 96);
            FMA4(O[0][0], p0, v0); FMA4(O[0][1], p0, v1);
            FMA4(O[0][2], p0, v2); FMA4(O[0][3], p0, v3);
            FMA4(O[1][0], p1, v0); FMA4(O[1][1], p1, v1);
            FMA4(O[1][2], p1, v2); FMA4(O[1][3], p1, v3);
        }
    }
#pragma unroll
    for (int i = 0; i < 2; i++) {
        const float inv = 1.0f / lsm[i];
        float* orow = out + (size_t)(qi * 64 + ty + 32 * i) * HDIM + h * HD + 4 * tx;
#pragma unroll
        for (int jj = 0; jj < 4; jj++) {
            float4 wv = O[i][jj];
            wv.x *= inv; wv.y *= inv; wv.z *= inv; wv.w *= inv;
            *(float4*)(orow + 32 * jj) = wv;
        }
    }
}

template <int N_, int K_>
__global__ __launch_bounds__(256) void sgemm(const float* __restrict__ A,
                                             const float* __restrict__ B,
                                             float* __restrict__ C) {
    __shared__ float As[8][128];
    __shared__ float Bs[8][128];
    const int tid = threadIdx.x;
    const int bm = blockIdx.y * 128;
    const int bn = blockIdx.x * 128;
    const int tx = tid & 15;
    const int ty = tid >> 4;
    const int lm = tid >> 1;
    const int lkq = (tid & 1) * 4;
    const int lr = tid >> 5;
    const int lnq = (tid & 31) * 4;
    float acc[8][8];
#pragma unroll
    for (int i = 0; i < 8; i++)
#pragma unroll
        for (int j = 0; j < 8; j++) acc[i][j] = 0.f;
    const float* Aptr = A + (size_t)(bm + lm) * K_ + lkq;
    const float* Bptr = B + (size_t)lr * N_ + bn + lnq;
    for (int k0 = 0; k0 < K_; k0 += 8) {
        float4 av = *(const float4*)Aptr;
        float4 bv = *(const float4*)Bptr;
        __syncthreads();
        As[lkq + 0][lm] = av.x;
        As[lkq + 1][lm] = av.y;
        As[lkq + 2][lm] = av.z;
        As[lkq + 3][lm] = av.w;
        *(float4*)&Bs[lr][lnq] = bv;
        __syncthreads();
        Aptr += 8;
        Bptr += (size_t)8 * N_;
#pragma unroll
        for (int kk = 0; kk < 8; kk++) {
            float4 a0 = *(const float4*)&As[kk][ty * 4];
            float4 a1 = *(const float4*)&As[kk][64 + ty * 4];
            float4 b0 = *(const float4*)&Bs[kk][tx * 4];
            float4 b1 = *(const float4*)&Bs[kk][64 + tx * 4];
            float a[8] = {a0.x, a0.y, a0.z, a0.w, a1.x, a1.y, a1.z, a1.w};
            float bb[8] = {b0.x, b0.y, b0.z, b0.w, b1.x, b1.y, b1.z, b1.w};
#pragma unroll
            for (int i = 0; i < 8; i++)
#pragma unroll
                for (int j = 0; j < 8; j++) acc[i][j] += a[i] * bb[j];
        }
    }
#pragma unroll
    for (int i = 0; i < 8; i++) {
        int row = bm + ((i < 4) ? (ty * 4 + i) : (64 + ty * 4 + i - 4));
        float4 c0 = {acc[i][0], acc[i][1], acc[i][2], acc[i][3]};
        float4 c1 = {acc[i][4], acc[i][5], acc[i][6], acc[i][7]};
        *(float4*)&C[(size_t)row * N_ + bn + tx * 4] = c0;
        *(float4*)&C[(size_t)row * N_ + bn + 64 + tx * 4] = c1;
    }
}

// ---------------------------------------------------------------------------
extern "C" void kernel_launch(void* const* d_in, const int* in_sizes, int n_in,
                              void* d_out, int out_size, void* d_ws, size_t ws_size,
                              hipStream_t stream) {
    const int*   positions = (const int*)d_in[0];
    const float* hidden    = (const float*)d_in[1];
    const float* Wqkv      = (const float*)d_in[2];
    const float* Wo        = (const float*)d_in[3];
    float* out = (float*)d_out;

    char* ws = (char*)d_ws;
    float*  qkv   = (float*)ws;                     // [0, 50331648)
    ushort* attnB = (ushort*)ws;                    // overlays dead qkv [0, 16777216)
    float*  Pk    = (float*)(ws + 16777216);        // split-K partial [16777216, 50331648)
    ushort* WqkvT = (ushort*)(ws + 50331648);       // 50331648
    ushort* WoT   = (ushort*)(ws + 100663296);      // 33554432
    ushort* hA    = (ushort*)(ws + 134217728);      // 16777216 (dead after gemm1)
    ushort* qkB   = (ushort*)(ws + 134217728);      // 25165824 overlays hA
    ushort* Vt    = (ushort*)(ws + 159383552);      // 4194304
    const size_t NEEDED = 163577856;

    if (ws_size >= NEEDED) {
        cast_bf16<<<dim3((T_TOK * HDIM) / 1024), 256, 0, stream>>>(hidden, hA);
        transpose_cast<HDIM, QKVN><<<dim3(QKVN / 64, HDIM / 32), 256, 0, stream>>>(Wqkv, WqkvT);
        transpose_cast<HDIM, HDIM><<<dim3(HDIM / 64, HDIM / 32), 256, 0, stream>>>(Wo, WoT);
        gemm_bf16_8ph<QKVN, HDIM, HDIM>
            <<<dim3((T_TOK / 256) * (QKVN / 256), 1), 512, 0, stream>>>(hA, WqkvT, qkv, qkv);
        rope_cast<<<dim3(T_TOK, 10), 256, 0, stream>>>(positions, qkv, qkB);
        vt_cast<<<dim3(T_TOK / 32, 32), 256, 0, stream>>>(qkv, Vt);
        flash_attn_mfma<<<dim3(512), 256, 0, stream>>>(qkB, Vt, attnB);
        gemm_bf16_8ph<HDIM, HDIM, HDIM / 2>
            <<<dim3((T_TOK / 256) * (HDIM / 256), 2), 512, 0, stream>>>(attnB, WoT, out, Pk);
        add_f32<<<dim3((T_TOK * HDIM) / 1024), 256, 0, stream>>>(out, Pk);
    } else {
        float* attn = qkv + (size_t)T_TOK * QKVN;
        sgemm<QKVN, HDIM><<<dim3(QKVN / 128, T_TOK / 128), 256, 0, stream>>>(hidden, Wqkv, qkv);
        rope_kernel<<<dim3(T_TOK, 10), 256, 0, stream>>>(positions, qkv);
        flash_attn_f32<<<dim3(1024), 256, 0, stream>>>(qkv, attn);
        sgemm<HDIM, HDIM><<<dim3(HDIM / 128, T_TOK / 128), 256, 0, stream>>>(attn, Wo, out);
    }
}

// Round 4
// 616.349 us; speedup vs baseline: 1.1949x; 1.0548x over previous
//
#include <hip/hip_runtime.h>
#include <math.h>

#define T_TOK 2048
#define HDIM  4096
#define QKVN  6144
#define NHEADS 32
#define HD    128
#define KV_OFF 4096
#define V_OFF  5120
#define SCALE 0.08838834764831843f

typedef __attribute__((ext_vector_type(8))) short short8;
typedef __attribute__((ext_vector_type(4))) float f32x4;
typedef __attribute__((ext_vector_type(16))) float f32x16;

__device__ __forceinline__ ushort f2bf(float f) {
    union { float f; unsigned u; } v; v.f = f;
    unsigned r = v.u + 0x7FFFu + ((v.u >> 16) & 1u);   // RNE
    return (ushort)(r >> 16);
}

// ---------------------------------------------------------------------------
// 256x256 8-phase bf16 MFMA GEMM (R1 schedule, best measured: 643 TF).
// C[M,N] = A[M,:]*B^T[N,:], row stride LDK, K-extent KC (split-K via
// blockIdx.y; kz=0 -> C0, kz=1 -> C1). 8 waves (2M x 4N), BK=64, 128 KiB LDS.
// Reads at top of phase (16/0/8/0), stage after reads, no explicit lgkm
// (compiler inserts fine-grained waits). vmcnt(6) at phase 4 forces tile t+1
// fully resident (queue 14 -> 6 retires all 8 of its loads).
// ---------------------------------------------------------------------------
template <int N_, int LDK, int KC>
__global__ __launch_bounds__(512, 2) void gemm_bf16_8ph(const ushort* __restrict__ A,
                                                        const ushort* __restrict__ B,
                                                        float* __restrict__ C0,
                                                        float* __restrict__ C1) {
    __shared__ __attribute__((aligned(16))) ushort As[2][2][8192];  // [buf][half][128*64]
    __shared__ __attribute__((aligned(16))) ushort Bs[2][2][8192];

    constexpr int NT = KC / 64;
    constexpr int NBN = N_ / 256;

    const int kz = blockIdx.y;
    float* __restrict__ C = kz ? C1 : C0;

    const int nwgx = (int)gridDim.x;
    const int bid = (int)blockIdx.x;
    const int swz = (nwgx & 7) ? bid : ((bid & 7) * (nwgx >> 3) + (bid >> 3));  // XCD swizzle
    const int bm = (swz / NBN) * 256;
    const int bn = (swz % NBN) * 256;

    const int tid = (int)threadIdx.x;
    const int w = tid >> 6;           // 0..7
    const int l = tid & 63;
    const int hfa = w >> 2;           // A half used by this wave
    const int hfb = (w & 3) >> 1;     // B half used by this wave
    const int wbr64 = (w & 1) * 4096; // row-offset*64 within B half

    // ds-read addressing: element idx = frag*1024 + (l&15)*64 + colswz
    const int arc = (l & 15) * 64;
    const int ac0 = ((((l >> 4) << 4)) ^ ((l & 7) << 4)) >> 1;
    const int ac1 = (((1 << 6) | ((l >> 4) << 4)) ^ ((l & 7) << 4)) >> 1;

    // stage source addressing (inverse swizzle folded into per-lane col)
    const int grow = w * 8 + (l >> 3);            // 0..63
    const int gcol = ((l & 7) ^ (l >> 3)) * 8;    // element col within 64
    const ushort* Ag = A + (size_t)kz * KC + (size_t)(bm + grow) * LDK + gcol;
    const ushort* Bg = B + (size_t)kz * KC + (size_t)(bn + grow) * LDK + gcol;

    auto ldsA = (__attribute__((address_space(3))) char*)&As[0][0][0];
    auto ldsB = (__attribute__((address_space(3))) char*)&Bs[0][0][0];
    const int wsl = w * 1024;

#define STG2(ldsbase, gsrc, bufi, hfi, kt)                                                              \
    do {                                                                                                \
        __builtin_amdgcn_global_load_lds(                                                               \
            (const __attribute__((address_space(1))) void*)((gsrc) + (size_t)((hfi) * 128) * LDK + (kt) * 64),       \
            (__attribute__((address_space(3))) void*)((ldsbase) + (bufi) * 32768 + (hfi) * 16384 + wsl), 16, 0, 0);  \
        __builtin_amdgcn_global_load_lds(                                                               \
            (const __attribute__((address_space(1))) void*)((gsrc) + (size_t)((hfi) * 128 + 64) * LDK + (kt) * 64),  \
            (__attribute__((address_space(3))) void*)((ldsbase) + (bufi) * 32768 + (hfi) * 16384 + 8192 + wsl), 16, 0, 0); \
    } while (0)

    // prologue: tile0 fully, then tile1 (B-h0,B-h1,A-h0)
    STG2(ldsB, Bg, 0, 0, 0);
    STG2(ldsB, Bg, 0, 1, 0);
    STG2(ldsA, Ag, 0, 0, 0);
    STG2(ldsA, Ag, 0, 1, 0);
    STG2(ldsB, Bg, 1, 0, 1);
    STG2(ldsB, Bg, 1, 1, 1);
    STG2(ldsA, Ag, 1, 0, 1);
    asm volatile("s_waitcnt vmcnt(6)" ::: "memory");   // tile0's 8 loads done
    __builtin_amdgcn_s_barrier();

    f32x4 acc[8][4];
#pragma unroll
    for (int i = 0; i < 8; i++)
#pragma unroll
        for (int j = 0; j < 4; j++) acc[i][j] = (f32x4){0.f, 0.f, 0.f, 0.f};

    short8 a0[4][2], a1[4][2], bq[4][2];

    int buf = 0;
    for (int t = 0; t < NT; ++t) {
        const int nb = buf ^ 1;
        const ushort* Abuf = &As[buf][hfa][0];
        const ushort* Bbuf = &Bs[buf][hfb][0] + wbr64;

        // ---- phase 1: read a0(8)+bq(8); stage A-h1(t+1); MFMA acc[0..3][0..1] ----
#pragma unroll
        for (int fi = 0; fi < 4; fi++) {
            a0[fi][0] = *(const short8*)(Abuf + fi * 1024 + arc + ac0);
            a0[fi][1] = *(const short8*)(Abuf + fi * 1024 + arc + ac1);
        }
#pragma unroll
        for (int fj = 0; fj < 4; fj++) {
            bq[fj][0] = *(const short8*)(Bbuf + fj * 1024 + arc + ac0);
            bq[fj][1] = *(const short8*)(Bbuf + fj * 1024 + arc + ac1);
        }
        if (t + 1 < NT) STG2(ldsA, Ag, nb, 1, t + 1);
        __builtin_amdgcn_s_barrier();
        __builtin_amdgcn_s_setprio(1);
#pragma unroll
        for (int fi = 0; fi < 4; fi++)
#pragma unroll
            for (int fj = 0; fj < 2; fj++)
#pragma unroll
                for (int s = 0; s < 2; s++)
                    acc[fi][fj] = __builtin_amdgcn_mfma_f32_16x16x32_bf16(a0[fi][s], bq[fj][s], acc[fi][fj], 0, 0, 0);
        __builtin_amdgcn_s_setprio(0);
        __builtin_amdgcn_s_barrier();

        // ---- phase 2: stage B-h0(t+2); MFMA acc[0..3][2..3] ----
        if (t + 2 < NT) STG2(ldsB, Bg, buf, 0, t + 2);
        __builtin_amdgcn_s_barrier();
        __builtin_amdgcn_s_setprio(1);
#pragma unroll
        for (int fi = 0; fi < 4; fi++)
#pragma unroll
            for (int fj = 2; fj < 4; fj++)
#pragma unroll
                for (int s = 0; s < 2; s++)
                    acc[fi][fj] = __builtin_amdgcn_mfma_f32_16x16x32_bf16(a0[fi][s], bq[fj][s], acc[fi][fj], 0, 0, 0);
        __builtin_amdgcn_s_setprio(0);
        __builtin_amdgcn_s_barrier();

        // ---- phase 3: read a1(8); stage B-h1(t+2); MFMA acc[4..7][2..3] ----
#pragma unroll
        for (int fi = 0; fi < 4; fi++) {
            a1[fi][0] = *(const short8*)(Abuf + (fi + 4) * 1024 + arc + ac0);
            a1[fi][1] = *(const short8*)(Abuf + (fi + 4) * 1024 + arc + ac1);
        }
        if (t + 2 < NT) STG2(ldsB, Bg, buf, 1, t + 2);
        __builtin_amdgcn_s_barrier();
        __builtin_amdgcn_s_setprio(1);
#pragma unroll
        for (int fi = 0; fi < 4; fi++)
#pragma unroll
            for (int fj = 2; fj < 4; fj++)
#pragma unroll
                for (int s = 0; s < 2; s++)
                    acc[fi + 4][fj] = __builtin_amdgcn_mfma_f32_16x16x32_bf16(a1[fi][s], bq[fj][s], acc[fi + 4][fj], 0, 0, 0);
        __builtin_amdgcn_s_setprio(0);
        __builtin_amdgcn_s_barrier();

        // ---- phase 4: stage A-h0(t+2); vmcnt(6); MFMA acc[4..7][0..1] ----
        if (t + 2 < NT) {
            STG2(ldsA, Ag, buf, 0, t + 2);
            asm volatile("s_waitcnt vmcnt(6)" ::: "memory");   // tile t+1 fully landed
        } else {
            asm volatile("s_waitcnt vmcnt(0)" ::: "memory");   // tail drain
        }
        __builtin_amdgcn_s_barrier();
        __builtin_amdgcn_s_setprio(1);
#pragma unroll
        for (int fi = 0; fi < 4; fi++)
#pragma unroll
            for (int fj = 0; fj < 2; fj++)
#pragma unroll
                for (int s = 0; s < 2; s++)
                    acc[fi + 4][fj] = __builtin_amdgcn_mfma_f32_16x16x32_bf16(a1[fi][s], bq[fj][s], acc[fi + 4][fj], 0, 0, 0);
        __builtin_amdgcn_s_setprio(0);
        __builtin_amdgcn_s_barrier();

        buf = nb;
    }
#undef STG2

    // epilogue: C-frag layout col=l&15, row=(l>>4)*4+r
    const int cn = bn + (w & 3) * 64 + (l & 15);
    const int rm = bm + hfa * 128 + ((l >> 4) << 2);
#pragma unroll
    for (int fi = 0; fi < 8; fi++)
#pragma unroll
        for (int fj = 0; fj < 4; fj++)
#pragma unroll
            for (int r = 0; r < 4; r++)
                C[(size_t)(rm + 16 * fi + r) * N_ + cn + 16 * fj] = acc[fi][fj][r];
}

// ---------------------------------------------------------------------------
__global__ __launch_bounds__(256) void add_f32(float* __restrict__ out,
                                               const float* __restrict__ p) {
    const int i = (blockIdx.x * 256 + threadIdx.x) * 4;
    float4 a = *(const float4*)(out + i);
    float4 b = *(const float4*)(p + i);
    a.x += b.x; a.y += b.y; a.z += b.z; a.w += b.w;
    *(float4*)(out + i) = a;
}

// ---------------------------------------------------------------------------
__global__ __launch_bounds__(256) void cast_bf16(const float* __restrict__ in,
                                                 ushort* __restrict__ outp) {
    const int i = (blockIdx.x * 256 + threadIdx.x) * 4;
    float4 v = *(const float4*)(in + i);
    ushort4 o = {f2bf(v.x), f2bf(v.y), f2bf(v.z), f2bf(v.w)};
    *(ushort4*)(outp + i) = o;
}

// ---------------------------------------------------------------------------
template <int K_, int N_>
__global__ __launch_bounds__(256) void transpose_cast(const float* __restrict__ W,
                                                      ushort* __restrict__ WT) {
    __shared__ float T[32 * 65];
    const int k0 = blockIdx.y * 32;
    const int n0 = blockIdx.x * 64;
    const int x = threadIdx.x & 63;
    const int y = threadIdx.x >> 6;
#pragma unroll
    for (int p = 0; p < 8; p++) {
        const int kk = p * 4 + y;
        T[kk * 65 + x] = W[(size_t)(k0 + kk) * N_ + n0 + x];
    }
    __syncthreads();
#pragma unroll
    for (int q = 0; q < 4; q++) {
        const int nl = q * 16 + (threadIdx.x >> 4);
        const int k2 = (threadIdx.x & 15) * 2;
        ushort2 o = {f2bf(T[k2 * 65 + nl]), f2bf(T[(k2 + 1) * 65 + nl])};
        *(ushort2*)&WT[(size_t)(n0 + nl) * K_ + k0 + k2] = o;
    }
}

// ---------------------------------------------------------------------------
// NeoX RoPE fp32 qkv -> bf16 qkB for q (scaled) and k heads. v cols unwritten.
// ---------------------------------------------------------------------------
__global__ __launch_bounds__(256) void rope_cast(const int* __restrict__ pos,
                                                 const float* __restrict__ qkv,
                                                 ushort* __restrict__ qkB) {
    const int t = blockIdx.x;
    const int slot = blockIdx.y * 4 + (threadIdx.x >> 6);   // 0..39
    const int d = threadIdx.x & 63;
    const float p = (float)pos[t];
    const float invf = exp2f(-(float)d * (19.931568569324174f / 64.0f));
    const float f = p * invf;
    const float c = cosf(f), s = sinf(f);
    const float sc = (slot < 32) ? SCALE : 1.0f;
    const float* base = qkv + (size_t)t * QKVN + slot * HD;
    ushort* ob = qkB + (size_t)t * QKVN + slot * HD;
    const float x1 = base[d];
    const float x2 = base[d + 64];
    ob[d]      = f2bf((x1 * c - x2 * s) * sc);
    ob[d + 64] = f2bf((x2 * c + x1 * s) * sc);
}

// ---------------------------------------------------------------------------
// V transpose: qkv fp32 v-part [t][5120 + c] -> Vt bf16 [c][t], c = kvh*128+d.
// ---------------------------------------------------------------------------
__global__ __launch_bounds__(256) void vt_cast(const float* __restrict__ qkv,
                                               ushort* __restrict__ Vt) {
    __shared__ float tile[32][33];
    const int t0 = blockIdx.x * 32;
    const int c0 = blockIdx.y * 32;
    const int tx = threadIdx.x & 31;
    const int ty = threadIdx.x >> 5;   // 0..7
#pragma unroll
    for (int i = 0; i < 4; i++) {
        const int tt = ty + 8 * i;
        tile[tt][tx] = qkv[(size_t)(t0 + tt) * QKVN + V_OFF + c0 + tx];
    }
    __syncthreads();
#pragma unroll
    for (int i = 0; i < 4; i++) {
        const int dd = ty + 8 * i;
        Vt[(size_t)(c0 + dd) * 2048 + t0 + tx] = f2bf(tile[tx][dd]);
    }
}

// ---------------------------------------------------------------------------
// MFMA flash attention, KVBLK=64: halves barriers/vmcnt waits per unit work,
// one softmax reduce + one O-rescale per 64 keys. Double-buffered staging,
// 8 global_load_lds per tile per wave, vmcnt(8).
// ---------------------------------------------------------------------------
__global__ __launch_bounds__(256, 2) void flash_attn_mfma(
        const ushort* __restrict__ qkB,
        const ushort* __restrict__ Vt,
        ushort* __restrict__ attnB) {
    __shared__ ushort Kf[2][16 * 512];   // [buf][16 frags x 1024 B]
    __shared__ ushort Vf[2][16 * 512];

    const int b = blockIdx.x;              // 512
    const int half = b >> 8;
    const int rest = b & 255;
    const int h = rest >> 3;               // 0..31
    const int q8 = rest & 7;
    const int qi = half ? (15 - q8) : q8;  // 0..15, paired for balance
    const int kvh = h >> 2;

    const int tid = threadIdx.x;
    const int w = tid >> 6;
    const int l = tid & 63;
    const int l31 = l & 31;
    const int hf = l >> 5;

    const int qg = qi * 128 + w * 32 + l31;   // this lane's q row

    short8 qf[8];
    {
        const ushort* qrow = qkB + (size_t)qg * QKVN + h * HD + hf * 8;
#pragma unroll
        for (int kt = 0; kt < 8; kt++)
            qf[kt] = *(const short8*)(qrow + kt * 16);
    }

    f32x16 O[4];
#pragma unroll
    for (int dt = 0; dt < 4; dt++)
#pragma unroll
        for (int r = 0; r < 16; r++) O[dt][r] = 0.f;
    float mcur = -INFINITY, lcur = 0.f;

    // K: wave w stages frags {2w,2w+1} (sub0 rows) and {8+2w,8+2w+1} (sub1).
    const ushort* kbase = qkB + (size_t)l31 * QKVN + KV_OFF + kvh * HD + (2 * w) * 16 + hf * 8;
    // V: wave w stages frags {4w..4w+3}: d rows w*32+l31, t chunks of 16.
    const ushort* vbase = Vt + ((size_t)(kvh * 128 + w * 32 + l31)) * 2048 + hf * 8;

    auto ldsK = (__attribute__((address_space(3))) char*)&Kf[0][0];
    auto ldsV = (__attribute__((address_space(3))) char*)&Vf[0][0];

    const int nst = 2 * qi + 2;              // 64-key tiles
    const int mylast = (4 * qi + w) >> 1;    // last tile this wave computes

#define GLD(src, dst) __builtin_amdgcn_global_load_lds(                              \
        (const __attribute__((address_space(1))) void*)(src),                        \
        (__attribute__((address_space(3))) void*)(dst), 16, 0, 0)

#define AST64(j, bb)                                                                 \
    do {                                                                             \
        const ushort* kg0 = kbase + (size_t)(j) * 64 * QKVN;                         \
        const ushort* kg1 = kg0 + (size_t)32 * QKVN;                                 \
        GLD(kg0,      ldsK + (bb) * 16384 + (2 * w) * 1024);                         \
        GLD(kg0 + 16, ldsK + (bb) * 16384 + (2 * w + 1) * 1024);                     \
        GLD(kg1,      ldsK + (bb) * 16384 + (8 + 2 * w) * 1024);                     \
        GLD(kg1 + 16, ldsK + (bb) * 16384 + (8 + 2 * w + 1) * 1024);                 \
        const ushort* vg = vbase + (j) * 64;                                         \
        GLD(vg,       ldsV + (bb) * 16384 + (4 * w + 0) * 1024);                     \
        GLD(vg + 16,  ldsV + (bb) * 16384 + (4 * w + 1) * 1024);                     \
        GLD(vg + 32,  ldsV + (bb) * 16384 + (4 * w + 2) * 1024);                     \
        GLD(vg + 48,  ldsV + (bb) * 16384 + (4 * w + 3) * 1024);                     \
    } while (0)

    AST64(0, 0);   // prologue: stage tile 0 into buf 0

    for (int j = 0; j < nst; j++) {
        const int buf = j & 1;
        __builtin_amdgcn_s_barrier();            // all waves done computing j-1
        if (j + 1 < nst) {
            AST64(j + 1, buf ^ 1);
            asm volatile("s_waitcnt vmcnt(8)" ::: "memory");   // tile j's loads landed
        } else {
            asm volatile("s_waitcnt vmcnt(0)" ::: "memory");
        }
        __builtin_amdgcn_s_barrier();            // everyone's tile-j loads visible

        if (j <= mylast) {  // wave-uniform predicate (w-dependent)
            const ushort* Kb = &Kf[buf][0];
            const ushort* Vb = &Vf[buf][0];
            // ---- S^T = K · Q^T (two 32-key sub-tiles) ----
            f32x16 S0, S1;
#pragma unroll
            for (int r = 0; r < 16; r++) { S0[r] = 0.f; S1[r] = 0.f; }
            __builtin_amdgcn_s_setprio(1);
#pragma unroll
            for (int kt = 0; kt < 8; kt++) {
                short8 k0 = *(const short8*)(Kb + kt * 512 + l * 8);
                S0 = __builtin_amdgcn_mfma_f32_32x32x16_bf16(k0, qf[kt], S0, 0, 0, 0);
            }
#pragma unroll
            for (int kt = 0; kt < 8; kt++) {
                short8 k1 = *(const short8*)(Kb + (8 + kt) * 512 + l * 8);
                S1 = __builtin_amdgcn_mfma_f32_32x32x16_bf16(k1, qf[kt], S1, 0, 0, 0);
            }
            __builtin_amdgcn_s_setprio(0);

            if (j == mylast) {
                const int sb = j * 64 + 4 * hf;
#pragma unroll
                for (int r = 0; r < 16; r++) {
                    const int sg = sb + (r & 3) + 8 * (r >> 2);
                    if (sg > qg) S0[r] = -INFINITY;
                    if (sg + 32 > qg) S1[r] = -INFINITY;
                }
            }
            float rmax = S0[0];
#pragma unroll
            for (int r = 1; r < 16; r++) rmax = fmaxf(rmax, S0[r]);
#pragma unroll
            for (int r = 0; r < 16; r++) rmax = fmaxf(rmax, S1[r]);
            rmax = fmaxf(rmax, __shfl_xor(rmax, 32));
            const float mnew = fmaxf(mcur, rmax);
            const float alpha = __expf(mcur - mnew);
            float rsum = 0.f;
#pragma unroll
            for (int r = 0; r < 16; r++) {
                S0[r] = __expf(S0[r] - mnew);
                rsum += S0[r];
            }
#pragma unroll
            for (int r = 0; r < 16; r++) {
                S1[r] = __expf(S1[r] - mnew);
                rsum += S1[r];
            }
            rsum += __shfl_xor(rsum, 32);
            lcur = lcur * alpha + rsum;
            mcur = mnew;

#pragma unroll
            for (int dt = 0; dt < 4; dt++)
#pragma unroll
                for (int r = 0; r < 16; r++) O[dt][r] *= alpha;

            // ---- build PV B-frags Pf[0..3] (ks 0..3 over 64 keys) ----
            short8 Pf[4];
            {
                unsigned pk[8], rk[8];
#pragma unroll
                for (int g = 0; g < 4; g++) {
                    pk[2 * g]     = (unsigned)f2bf(S0[4 * g])     | ((unsigned)f2bf(S0[4 * g + 1]) << 16);
                    pk[2 * g + 1] = (unsigned)f2bf(S0[4 * g + 2]) | ((unsigned)f2bf(S0[4 * g + 3]) << 16);
                }
#pragma unroll
                for (int i = 0; i < 8; i++) rk[i] = (unsigned)__shfl_xor((int)pk[i], 32);
#pragma unroll
                for (int kt2 = 0; kt2 < 2; kt2++) {
                    const int g = 2 * kt2 + hf;
                    union { unsigned u[4]; short8 s; } cvt;
                    cvt.u[0] = hf ? rk[2 * g]     : pk[2 * g];
                    cvt.u[1] = hf ? rk[2 * g + 1] : pk[2 * g + 1];
                    cvt.u[2] = hf ? pk[2 * g]     : rk[2 * g];
                    cvt.u[3] = hf ? pk[2 * g + 1] : rk[2 * g + 1];
                    Pf[kt2] = cvt.s;
                }
#pragma unroll
                for (int g = 0; g < 4; g++) {
                    pk[2 * g]     = (unsigned)f2bf(S1[4 * g])     | ((unsigned)f2bf(S1[4 * g + 1]) << 16);
                    pk[2 * g + 1] = (unsigned)f2bf(S1[4 * g + 2]) | ((unsigned)f2bf(S1[4 * g + 3]) << 16);
                }
#pragma unroll
                for (int i = 0; i < 8; i++) rk[i] = (unsigned)__shfl_xor((int)pk[i], 32);
#pragma unroll
                for (int kt2 = 0; kt2 < 2; kt2++) {
                    const int g = 2 * kt2 + hf;
                    union { unsigned u[4]; short8 s; } cvt;
                    cvt.u[0] = hf ? rk[2 * g]     : pk[2 * g];
                    cvt.u[1] = hf ? rk[2 * g + 1] : pk[2 * g + 1];
                    cvt.u[2] = hf ? pk[2 * g]     : rk[2 * g];
                    cvt.u[3] = hf ? pk[2 * g + 1] : rk[2 * g + 1];
                    Pf[2 + kt2] = cvt.s;
                }
            }

            // ---- O^T += V^T · P^T ----
            __builtin_amdgcn_s_setprio(1);
#pragma unroll
            for (int dt = 0; dt < 4; dt++)
#pragma unroll
                for (int ks = 0; ks < 4; ks++) {
                    short8 afV = *(const short8*)(Vb + (dt * 4 + ks) * 512 + l * 8);
                    O[dt] = __builtin_amdgcn_mfma_f32_32x32x16_bf16(afV, Pf[ks], O[dt], 0, 0, 0);
                }
            __builtin_amdgcn_s_setprio(0);
        }
    }
#undef AST64
#undef GLD

    const float inv = 1.0f / lcur;
    ushort* orow = attnB + (size_t)qg * HDIM + h * HD + 4 * hf;
#pragma unroll
    for (int dt = 0; dt < 4; dt++)
#pragma unroll
        for (int rg = 0; rg < 4; rg++) {
            ushort4 o;
            o.x = f2bf(O[dt][4 * rg + 0] * inv);
            o.y = f2bf(O[dt][4 * rg + 1] * inv);
            o.z = f2bf(O[dt][4 * rg + 2] * inv);
            o.w = f2bf(O[dt][4 * rg + 3] * inv);
            *(ushort4*)(orow + dt * 32 + 8 * rg) = o;
        }
}

// ---------------------------------------------------------------------------
// Fallback fp32 path — used only if workspace is too small.
// ---------------------------------------------------------------------------
__global__ __launch_bounds__(256) void rope_kernel(const int* __restrict__ pos,
                                                   float* __restrict__ qkv) {
    const int t = blockIdx.x;
    const int head = blockIdx.y * 4 + (threadIdx.x >> 6);
    const int d = threadIdx.x & 63;
    const float p = (float)pos[t];
    const float invf = exp2f(-(float)d * (19.931568569324174f / 64.0f));
    const float f = p * invf;
    const float c = cosf(f), s = sinf(f);
    float* base = qkv + (size_t)t * QKVN + head * HD;
    const float x1 = base[d];
    const float x2 = base[d + 64];
    base[d]      = x1 * c - x2 * s;
    base[d + 64] = x2 * c + x1 * s;
}

#define DOT4(acc, a, b) acc += (a).x*(b).x + (a).y*(b).y + (a).z*(b).z + (a).w*(b).w
#define FMA4(o, p, v) { (o).x += (p)*(v).x; (o).y += (p)*(v).y; (o).z += (p)*(v).z; (o).w += (p)*(v).w; }

__global__ __launch_bounds__(256, 2) void flash_attn_f32(const float* __restrict__ qkv,
                                                         float* __restrict__ out) {
    __shared__ float Qs[64 * 132];
    __shared__ float KVs[32 * 132];
    __shared__ float Ps[64 * 34];
    const int b = blockIdx.x;
    const int half = (b >> 9) & 1;
    const int rest = b & 511;
    const int h = rest >> 4;
    const int qlo = rest & 15;
    const int qi = half ? (31 - qlo) : qlo;
    const int kvh = h >> 2;
    const int tid = threadIdx.x;
    const int tx = tid & 7;
    const int ty = tid >> 3;
    {
        const float* qbase = qkv + (size_t)(qi * 64) * QKVN + h * HD;
#pragma unroll
        for (int r = 0; r < 8; r++) {
            int idx = r * 256 + tid;
            int qrow = idx >> 5;
            int d = (idx & 31) * 4;
            float4 v = *(const float4*)(qbase + (size_t)qrow * QKVN + d);
            v.x *= SCALE; v.y *= SCALE; v.z *= SCALE; v.w *= SCALE;
            *(float4*)(Qs + qrow * 132 + d) = v;
        }
    }
    float m[2], lsm[2];
    float4 O[2][4];
#pragma unroll
    for (int i = 0; i < 2; i++) {
        m[i] = -INFINITY; lsm[i] = 0.f;
#pragma unroll
        for (int jj = 0; jj < 4; jj++) O[i][jj] = make_float4(0.f, 0.f, 0.f, 0.f);
    }
    const float* kbase = qkv + KV_OFF + kvh * HD;
    const float* vbase = qkv + V_OFF + kvh * HD;
    const int qg0 = qi * 64 + ty;
    const int nst = 2 * qi + 2;
    for (int st = 0; st < nst; st++) {
        __syncthreads();
#pragma unroll
        for (int r = 0; r < 4; r++) {
            int idx = r * 256 + tid;
            int srow = idx >> 5;
            int d = (idx & 31) * 4;
            *(float4*)(KVs + srow * 132 + d) =
                *(const float4*)(kbase + (size_t)(st * 32 + srow) * QKVN + d);
        }
        __syncthreads();
        float S[2][4];
#pragma unroll
        for (int i = 0; i < 2; i++)
#pragma unroll
            for (int j = 0; j < 4; j++) S[i][j] = 0.f;
#pragma unroll 4
        for (int kk = 0; kk < HD; kk += 4) {
            float4 q0 = *(const float4*)(Qs + ty * 132 + kk);
            float4 q1 = *(const float4*)(Qs + (ty + 32) * 132 + kk);
            float4 k0 = *(const float4*)(KVs + tx * 132 + kk);
            float4 k1 = *(const float4*)(KVs + (tx + 8) * 132 + kk);
            float4 k2 = *(const float4*)(KVs + (tx + 16) * 132 + kk);
            float4 k3 = *(const float4*)(KVs + (tx + 24) * 132 + kk);
            DOT4(S[0][0], q0, k0); DOT4(S[0][1], q0, k1);
            DOT4(S[0][2], q0, k2); DOT4(S[0][3], q0, k3);
            DOT4(S[1][0], q1, k0); DOT4(S[1][1], q1, k1);
            DOT4(S[1][2], q1, k2); DOT4(S[1][3], q1, k3);
        }
        const int sg0 = st * 32 + tx;
        float alpha[2];
#pragma unroll
        for (int i = 0; i < 2; i++) {
            const int qg = qg0 + 32 * i;
            float rmax = -INFINITY;
#pragma unroll
            for (int j = 0; j < 4; j++) {
                if (sg0 + 8 * j > qg) S[i][j] = -INFINITY;
                rmax = fmaxf(rmax, S[i][j]);
            }
#pragma unroll
            for (int off = 1; off < 8; off <<= 1)
                rmax = fmaxf(rmax, __shfl_xor(rmax, off));
            const float mnew = fmaxf(m[i], rmax);
            alpha[i] = __expf(m[i] - mnew);
            float rsum = 0.f;
#pragma unroll
            for (int j = 0; j < 4; j++) {
                S[i][j] = __expf(S[i][j] - mnew);
                rsum += S[i][j];
            }
#pragma unroll
            for (int off = 1; off < 8; off <<= 1)
                rsum += __shfl_xor(rsum, off);
            lsm[i] = lsm[i] * alpha[i] + rsum;
            m[i] = mnew;
        }
#pragma unroll
        for (int i = 0; i < 2; i++)
#pragma unroll
            for (int j = 0; j < 4; j++)
                Ps[(ty + 32 * i) * 34 + tx + 8 * j] = S[i][j];
        __syncthreads();
#pragma unroll
        for (int r = 0; r < 4; r++) {
            int idx = r * 256 + tid;
            int srow = idx >> 5;
            int d = (idx & 31) * 4;
            *(float4*)(KVs + srow * 132 + d) =
                *(const float4*)(vbase + (size_t)(st * 32 + srow) * QKVN + d);
        }
        __syncthreads();
#pragma unroll
        for (int i = 0; i < 2; i++) {
            const float a = alpha[i];
#pragma unroll
            for (int jj = 0; jj < 4; jj++) {
                O[i][jj].x *= a; O[i][jj].y *= a; O[i][jj].z *= a; O[i][jj].w *= a;
            }
        }
#pragma unroll 4
        for (int s = 0; s < 32; s++) {
            float p0 = Ps[ty * 34 + s];
            float p1 = Ps[(ty + 32) * 34 + s];
            const float* vr = KVs + s * 132 + 4 * tx;
            float4 v0 = *(const float4*)(vr);
            float4 v1 = *(const float4*)(vr + 32);
            float4 v2 = *(const float4*)(vr + 64);
            float4 v3 = *(const float4*)(vr + 96);
            FMA4(O[0][0], p0, v0); FMA4(O[0][1], p0, v1);
            FMA4(O[0][2], p0, v2); FMA4(O[0][3], p0, v3);
            FMA4(O[1][0], p1, v0); FMA4(O[1][1], p1, v1);
            FMA4(O[1][2], p1, v2); FMA4(O[1][3], p1, v3);
        }
    }
#pragma unroll
    for (int i = 0; i < 2; i++) {
        const float inv = 1.0f / lsm[i];
        float* orow = out + (size_t)(qi * 64 + ty + 32 * i) * HDIM + h * HD + 4 * tx;
#pragma unroll
        for (int jj = 0; jj < 4; jj++) {
            float4 wv = O[i][jj];
            wv.x *= inv; wv.y *= inv; wv.z *= inv; wv.w *= inv;
            *(float4*)(orow + 32 * jj) = wv;
        }
    }
}

template <int N_, int K_>
__global__ __launch_bounds__(256) void sgemm(const float* __restrict__ A,
                                             const float* __restrict__ B,
                                             float* __restrict__ C) {
    __shared__ float As[8][128];
    __shared__ float Bs[8][128];
    const int tid = threadIdx.x;
    const int bm = blockIdx.y * 128;
    const int bn = blockIdx.x * 128;
    const int tx = tid & 15;
    const int ty = tid >> 4;
    const int lm = tid >> 1;
    const int lkq = (tid & 1) * 4;
    const int lr = tid >> 5;
    const int lnq = (tid & 31) * 4;
    float acc[8][8];
#pragma unroll
    for (int i = 0; i < 8; i++)
#pragma unroll
        for (int j = 0; j < 8; j++) acc[i][j] = 0.f;
    const float* Aptr = A + (size_t)(bm + lm) * K_ + lkq;
    const float* Bptr = B + (size_t)lr * N_ + bn + lnq;
    for (int k0 = 0; k0 < K_; k0 += 8) {
        float4 av = *(const float4*)Aptr;
        float4 bv = *(const float4*)Bptr;
        __syncthreads();
        As[lkq + 0][lm] = av.x;
        As[lkq + 1][lm] = av.y;
        As[lkq + 2][lm] = av.z;
        As[lkq + 3][lm] = av.w;
        *(float4*)&Bs[lr][lnq] = bv;
        __syncthreads();
        Aptr += 8;
        Bptr += (size_t)8 * N_;
#pragma unroll
        for (int kk = 0; kk < 8; kk++) {
            float4 a0 = *(const float4*)&As[kk][ty * 4];
            float4 a1 = *(const float4*)&As[kk][64 + ty * 4];
            float4 b0 = *(const float4*)&Bs[kk][tx * 4];
            float4 b1 = *(const float4*)&Bs[kk][64 + tx * 4];
            float a[8] = {a0.x, a0.y, a0.z, a0.w, a1.x, a1.y, a1.z, a1.w};
            float bb[8] = {b0.x, b0.y, b0.z, b0.w, b1.x, b1.y, b1.z, b1.w};
#pragma unroll
            for (int i = 0; i < 8; i++)
#pragma unroll
                for (int j = 0; j < 8; j++) acc[i][j] += a[i] * bb[j];
        }
    }
#pragma unroll
    for (int i = 0; i < 8; i++) {
        int row = bm + ((i < 4) ? (ty * 4 + i) : (64 + ty * 4 + i - 4));
        float4 c0 = {acc[i][0], acc[i][1], acc[i][2], acc[i][3]};
        float4 c1 = {acc[i][4], acc[i][5], acc[i][6], acc[i][7]};
        *(float4*)&C[(size_t)row * N_ + bn + tx * 4] = c0;
        *(float4*)&C[(size_t)row * N_ + bn + 64 + tx * 4] = c1;
    }
}

// ---------------------------------------------------------------------------
extern "C" void kernel_launch(void* const* d_in, const int* in_sizes, int n_in,
                              void* d_out, int out_size, void* d_ws, size_t ws_size,
                              hipStream_t stream) {
    const int*   positions = (const int*)d_in[0];
    const float* hidden    = (const float*)d_in[1];
    const float* Wqkv      = (const float*)d_in[2];
    const float* Wo        = (const float*)d_in[3];
    float* out = (float*)d_out;

    char* ws = (char*)d_ws;
    float*  qkv   = (float*)ws;                     // [0, 50331648)
    ushort* attnB = (ushort*)ws;                    // overlays dead qkv [0, 16777216)
    float*  Pk    = (float*)(ws + 16777216);        // split-K partial [16777216, 50331648)
    ushort* WqkvT = (ushort*)(ws + 50331648);       // 50331648
    ushort* WoT   = (ushort*)(ws + 100663296);      // 33554432
    ushort* hA    = (ushort*)(ws + 134217728);      // 16777216 (dead after gemm1)
    ushort* qkB   = (ushort*)(ws + 134217728);      // 25165824 overlays hA
    ushort* Vt    = (ushort*)(ws + 159383552);      // 4194304
    const size_t NEEDED = 163577856;

    if (ws_size >= NEEDED) {
        cast_bf16<<<dim3((T_TOK * HDIM) / 1024), 256, 0, stream>>>(hidden, hA);
        transpose_cast<HDIM, QKVN><<<dim3(QKVN / 64, HDIM / 32), 256, 0, stream>>>(Wqkv, WqkvT);
        transpose_cast<HDIM, HDIM><<<dim3(HDIM / 64, HDIM / 32), 256, 0, stream>>>(Wo, WoT);
        gemm_bf16_8ph<QKVN, HDIM, HDIM>
            <<<dim3((T_TOK / 256) * (QKVN / 256), 1), 512, 0, stream>>>(hA, WqkvT, qkv, qkv);
        rope_cast<<<dim3(T_TOK, 10), 256, 0, stream>>>(positions, qkv, qkB);
        vt_cast<<<dim3(T_TOK / 32, 32), 256, 0, stream>>>(qkv, Vt);
        flash_attn_mfma<<<dim3(512), 256, 0, stream>>>(qkB, Vt, attnB);
        gemm_bf16_8ph<HDIM, HDIM, HDIM / 2>
            <<<dim3((T_TOK / 256) * (HDIM / 256), 2), 512, 0, stream>>>(attnB, WoT, out, Pk);
        add_f32<<<dim3((T_TOK * HDIM) / 1024), 256, 0, stream>>>(out, Pk);
    } else {
        float* attn = qkv + (size_t)T_TOK * QKVN;
        sgemm<QKVN, HDIM><<<dim3(QKVN / 128, T_TOK / 128), 256, 0, stream>>>(hidden, Wqkv, qkv);
        rope_kernel<<<dim3(T_TOK, 10), 256, 0, stream>>>(positions, qkv);
        flash_attn_f32<<<dim3(1024), 256, 0, stream>>>(qkv, attn);
        sgemm<HDIM, HDIM><<<dim3(HDIM / 128, T_TOK / 128), 256, 0, stream>>>(attn, Wo, out);
    }
}

// Round 5
// 604.247 us; speedup vs baseline: 1.2188x; 1.0200x over previous
//
#include <hip/hip_runtime.h>
#include <math.h>

#define T_TOK 2048
#define HDIM  4096
#define QKVN  6144
#define NHEADS 32
#define HD    128
#define KV_OFF 4096
#define V_OFF  5120
#define SCALE 0.08838834764831843f

typedef __attribute__((ext_vector_type(8))) short short8;
typedef __attribute__((ext_vector_type(4))) float f32x4;
typedef __attribute__((ext_vector_type(16))) float f32x16;

__device__ __forceinline__ ushort f2bf(float f) {
    union { float f; unsigned u; } v; v.f = f;
    unsigned r = v.u + 0x7FFFu + ((v.u >> 16) & 1u);   // RNE
    return (ushort)(r >> 16);
}

// ---------------------------------------------------------------------------
// 256x256 8-phase bf16 MFMA GEMM (R1/R4 schedule, best measured ~656 TF).
// C[M,N] = A[M,:]*B^T[N,:], row stride LDK, K-extent KC (split-K blockIdx.y).
// MODE 0: plain fp32 C write (kz -> C0/C1).
// MODE 1: fused qkv epilogue — NeoX rope -> qkB bf16 for cols < 5120 (q scaled),
//         V-transpose -> Vt bf16 [c][t] for cols >= 5120. No fp32 C at all.
//         Partner exchange + transpose via strip-staged LDS (reuses As).
// ---------------------------------------------------------------------------
template <int N_, int LDK, int KC, int MODE>
__global__ __launch_bounds__(512, 2) void gemm_bf16_8ph(const ushort* __restrict__ A,
                                                        const ushort* __restrict__ B,
                                                        float* __restrict__ C0,
                                                        float* __restrict__ C1,
                                                        const int* __restrict__ pos,
                                                        ushort* __restrict__ qkB,
                                                        ushort* __restrict__ Vt) {
    __shared__ __attribute__((aligned(16))) ushort As[2][2][8192];  // [buf][half][128*64]
    __shared__ __attribute__((aligned(16))) ushort Bs[2][2][8192];

    constexpr int NT = KC / 64;
    constexpr int NBN = N_ / 256;

    const int kz = blockIdx.y;

    const int nwgx = (int)gridDim.x;
    const int bid = (int)blockIdx.x;
    const int swz = (nwgx & 7) ? bid : ((bid & 7) * (nwgx >> 3) + (bid >> 3));  // XCD swizzle
    const int bm = (swz / NBN) * 256;
    const int bn = (swz % NBN) * 256;

    const int tid = (int)threadIdx.x;
    const int w = tid >> 6;           // 0..7
    const int l = tid & 63;
    const int hfa = w >> 2;           // A half used by this wave
    const int hfb = (w & 3) >> 1;     // B half used by this wave
    const int wbr64 = (w & 1) * 4096; // row-offset*64 within B half

    // ds-read addressing: element idx = frag*1024 + (l&15)*64 + colswz
    const int arc = (l & 15) * 64;
    const int ac0 = ((((l >> 4) << 4)) ^ ((l & 7) << 4)) >> 1;
    const int ac1 = (((1 << 6) | ((l >> 4) << 4)) ^ ((l & 7) << 4)) >> 1;

    // stage source addressing (inverse swizzle folded into per-lane col)
    const int grow = w * 8 + (l >> 3);            // 0..63
    const int gcol = ((l & 7) ^ (l >> 3)) * 8;    // element col within 64
    const ushort* Ag = A + (size_t)kz * KC + (size_t)(bm + grow) * LDK + gcol;
    const ushort* Bg = B + (size_t)kz * KC + (size_t)(bn + grow) * LDK + gcol;

    auto ldsA = (__attribute__((address_space(3))) char*)&As[0][0][0];
    auto ldsB = (__attribute__((address_space(3))) char*)&Bs[0][0][0];
    const int wsl = w * 1024;

#define STG2(ldsbase, gsrc, bufi, hfi, kt)                                                              \
    do {                                                                                                \
        __builtin_amdgcn_global_load_lds(                                                               \
            (const __attribute__((address_space(1))) void*)((gsrc) + (size_t)((hfi) * 128) * LDK + (kt) * 64),       \
            (__attribute__((address_space(3))) void*)((ldsbase) + (bufi) * 32768 + (hfi) * 16384 + wsl), 16, 0, 0);  \
        __builtin_amdgcn_global_load_lds(                                                               \
            (const __attribute__((address_space(1))) void*)((gsrc) + (size_t)((hfi) * 128 + 64) * LDK + (kt) * 64),  \
            (__attribute__((address_space(3))) void*)((ldsbase) + (bufi) * 32768 + (hfi) * 16384 + 8192 + wsl), 16, 0, 0); \
    } while (0)

    // prologue: tile0 fully, then tile1 (B-h0,B-h1,A-h0)
    STG2(ldsB, Bg, 0, 0, 0);
    STG2(ldsB, Bg, 0, 1, 0);
    STG2(ldsA, Ag, 0, 0, 0);
    STG2(ldsA, Ag, 0, 1, 0);
    STG2(ldsB, Bg, 1, 0, 1);
    STG2(ldsB, Bg, 1, 1, 1);
    STG2(ldsA, Ag, 1, 0, 1);
    asm volatile("s_waitcnt vmcnt(6)" ::: "memory");   // tile0's 8 loads done
    __builtin_amdgcn_s_barrier();

    f32x4 acc[8][4];
#pragma unroll
    for (int i = 0; i < 8; i++)
#pragma unroll
        for (int j = 0; j < 4; j++) acc[i][j] = (f32x4){0.f, 0.f, 0.f, 0.f};

    short8 a0[4][2], a1[4][2], bq[4][2];

    int buf = 0;
    for (int t = 0; t < NT; ++t) {
        const int nb = buf ^ 1;
        const ushort* Abuf = &As[buf][hfa][0];
        const ushort* Bbuf = &Bs[buf][hfb][0] + wbr64;

        // ---- phase 1: read a0(8)+bq(8); stage A-h1(t+1); MFMA acc[0..3][0..1] ----
#pragma unroll
        for (int fi = 0; fi < 4; fi++) {
            a0[fi][0] = *(const short8*)(Abuf + fi * 1024 + arc + ac0);
            a0[fi][1] = *(const short8*)(Abuf + fi * 1024 + arc + ac1);
        }
#pragma unroll
        for (int fj = 0; fj < 4; fj++) {
            bq[fj][0] = *(const short8*)(Bbuf + fj * 1024 + arc + ac0);
            bq[fj][1] = *(const short8*)(Bbuf + fj * 1024 + arc + ac1);
        }
        if (t + 1 < NT) STG2(ldsA, Ag, nb, 1, t + 1);
        __builtin_amdgcn_s_barrier();
        __builtin_amdgcn_s_setprio(1);
#pragma unroll
        for (int fi = 0; fi < 4; fi++)
#pragma unroll
            for (int fj = 0; fj < 2; fj++)
#pragma unroll
                for (int s = 0; s < 2; s++)
                    acc[fi][fj] = __builtin_amdgcn_mfma_f32_16x16x32_bf16(a0[fi][s], bq[fj][s], acc[fi][fj], 0, 0, 0);
        __builtin_amdgcn_s_setprio(0);
        __builtin_amdgcn_s_barrier();

        // ---- phase 2: stage B-h0(t+2); MFMA acc[0..3][2..3] ----
        if (t + 2 < NT) STG2(ldsB, Bg, buf, 0, t + 2);
        __builtin_amdgcn_s_barrier();
        __builtin_amdgcn_s_setprio(1);
#pragma unroll
        for (int fi = 0; fi < 4; fi++)
#pragma unroll
            for (int fj = 2; fj < 4; fj++)
#pragma unroll
                for (int s = 0; s < 2; s++)
                    acc[fi][fj] = __builtin_amdgcn_mfma_f32_16x16x32_bf16(a0[fi][s], bq[fj][s], acc[fi][fj], 0, 0, 0);
        __builtin_amdgcn_s_setprio(0);
        __builtin_amdgcn_s_barrier();

        // ---- phase 3: read a1(8); stage B-h1(t+2); MFMA acc[4..7][2..3] ----
#pragma unroll
        for (int fi = 0; fi < 4; fi++) {
            a1[fi][0] = *(const short8*)(Abuf + (fi + 4) * 1024 + arc + ac0);
            a1[fi][1] = *(const short8*)(Abuf + (fi + 4) * 1024 + arc + ac1);
        }
        if (t + 2 < NT) STG2(ldsB, Bg, buf, 1, t + 2);
        __builtin_amdgcn_s_barrier();
        __builtin_amdgcn_s_setprio(1);
#pragma unroll
        for (int fi = 0; fi < 4; fi++)
#pragma unroll
            for (int fj = 2; fj < 4; fj++)
#pragma unroll
                for (int s = 0; s < 2; s++)
                    acc[fi + 4][fj] = __builtin_amdgcn_mfma_f32_16x16x32_bf16(a1[fi][s], bq[fj][s], acc[fi + 4][fj], 0, 0, 0);
        __builtin_amdgcn_s_setprio(0);
        __builtin_amdgcn_s_barrier();

        // ---- phase 4: stage A-h0(t+2); vmcnt(6); MFMA acc[4..7][0..1] ----
        if (t + 2 < NT) {
            STG2(ldsA, Ag, buf, 0, t + 2);
            asm volatile("s_waitcnt vmcnt(6)" ::: "memory");   // tile t+1 fully landed
        } else {
            asm volatile("s_waitcnt vmcnt(0)" ::: "memory");   // tail drain
        }
        __builtin_amdgcn_s_barrier();
        __builtin_amdgcn_s_setprio(1);
#pragma unroll
        for (int fi = 0; fi < 4; fi++)
#pragma unroll
            for (int fj = 0; fj < 2; fj++)
#pragma unroll
                for (int s = 0; s < 2; s++)
                    acc[fi + 4][fj] = __builtin_amdgcn_mfma_f32_16x16x32_bf16(a1[fi][s], bq[fj][s], acc[fi + 4][fj], 0, 0, 0);
        __builtin_amdgcn_s_setprio(0);
        __builtin_amdgcn_s_barrier();

        buf = nb;
    }
#undef STG2

    if constexpr (MODE == 0) {
        // epilogue: C-frag layout col=l&15, row=(l>>4)*4+r
        float* __restrict__ C = kz ? C1 : C0;
        const int cn = bn + (w & 3) * 64 + (l & 15);
        const int rm = bm + hfa * 128 + ((l >> 4) << 2);
#pragma unroll
        for (int fi = 0; fi < 8; fi++)
#pragma unroll
            for (int fj = 0; fj < 4; fj++)
#pragma unroll
                for (int r = 0; r < 4; r++)
                    C[(size_t)(rm + 16 * fi + r) * N_ + cn + 16 * fj] = acc[fi][fj][r];
    } else {
        // ---- fused qkv epilogue ----
        // strip = 32 rows (2 hfa x 16) x 256 cols fp32, stride 260 dwords
        float* Ls = (float*)&As[0][0][0];   // 2*16*260*4 = 33280 B, reuses dead K-loop LDS
        const bool isV = (bn >= V_OFF);
        const int q = w & 3;
        const int r4 = (l >> 4) << 2;
#pragma unroll
        for (int fi = 0; fi < 8; fi++) {
            // write strip: Ls[(hfa*16 + r4+r)*260 + q*64 + (l&15) + 16*fj]
#pragma unroll
            for (int fj = 0; fj < 4; fj++)
#pragma unroll
                for (int r = 0; r < 4; r++)
                    Ls[(hfa * 16 + r4 + r) * 260 + q * 64 + (l & 15) + 16 * fj] = acc[fi][fj][r];
            __builtin_amdgcn_s_barrier();
            if (!isV) {
                const int trow = bm + hfa * 128 + 16 * fi + r4;
#pragma unroll
                for (int r = 0; r < 4; r++) {
                    const int t = trow + r;
                    const float p = (float)pos[t];
#pragma unroll
                    for (int fj = 0; fj < 4; fj++) {
                        const int cr = q * 64 + (l & 15) + 16 * fj;
                        const int dd = cr & 127;
                        const int d64 = dd & 63;
                        const float own = acc[fi][fj][r];
                        const float prt = Ls[(hfa * 16 + r4 + r) * 260 + (cr ^ 64)];
                        const float invf = exp2f(-(float)d64 * (19.931568569324174f / 64.0f));
                        const float ang = p * invf;
                        const float cf = __cosf(ang), sf = __sinf(ang);
                        const float o = (dd < 64) ? (own * cf - prt * sf) : (own * cf + prt * sf);
                        const float sc = (bn + cr < KV_OFF) ? SCALE : 1.0f;
                        qkB[(size_t)t * QKVN + bn + cr] = f2bf(o * sc);
                    }
                }
            } else {
                // V-transpose out of the strip: thread -> (vc = tid>>1, hh = tid&1)
                const int vcr = tid >> 1;
                const int hh = tid & 1;
                union { ushort u[16]; short8 s[2]; } tmp;
#pragma unroll
                for (int rr = 0; rr < 16; rr++)
                    tmp.u[rr] = f2bf(Ls[(hh * 16 + rr) * 260 + vcr]);
                ushort* dst = Vt + (size_t)(bn - V_OFF + vcr) * 2048 + bm + hh * 128 + 16 * fi;
                *(short8*)dst = tmp.s[0];
                *(short8*)(dst + 8) = tmp.s[1];
            }
            __builtin_amdgcn_s_barrier();
        }
    }
}

// ---------------------------------------------------------------------------
__global__ __launch_bounds__(256) void add_f32(float* __restrict__ out,
                                               const float* __restrict__ p) {
    const int i = (blockIdx.x * 256 + threadIdx.x) * 4;
    float4 a = *(const float4*)(out + i);
    float4 b = *(const float4*)(p + i);
    a.x += b.x; a.y += b.y; a.z += b.z; a.w += b.w;
    *(float4*)(out + i) = a;
}

// ---------------------------------------------------------------------------
__global__ __launch_bounds__(256) void cast_bf16(const float* __restrict__ in,
                                                 ushort* __restrict__ outp) {
    const int i = (blockIdx.x * 256 + threadIdx.x) * 4;
    float4 v = *(const float4*)(in + i);
    ushort4 o = {f2bf(v.x), f2bf(v.y), f2bf(v.z), f2bf(v.w)};
    *(ushort4*)(outp + i) = o;
}

// ---------------------------------------------------------------------------
template <int K_, int N_>
__global__ __launch_bounds__(256) void transpose_cast(const float* __restrict__ W,
                                                      ushort* __restrict__ WT) {
    __shared__ float T[32 * 65];
    const int k0 = blockIdx.y * 32;
    const int n0 = blockIdx.x * 64;
    const int x = threadIdx.x & 63;
    const int y = threadIdx.x >> 6;
#pragma unroll
    for (int p = 0; p < 8; p++) {
        const int kk = p * 4 + y;
        T[kk * 65 + x] = W[(size_t)(k0 + kk) * N_ + n0 + x];
    }
    __syncthreads();
#pragma unroll
    for (int q = 0; q < 4; q++) {
        const int nl = q * 16 + (threadIdx.x >> 4);
        const int k2 = (threadIdx.x & 15) * 2;
        ushort2 o = {f2bf(T[k2 * 65 + nl]), f2bf(T[(k2 + 1) * 65 + nl])};
        *(ushort2*)&WT[(size_t)(n0 + nl) * K_ + k0 + k2] = o;
    }
}

// ---------------------------------------------------------------------------
// MFMA flash attention, KVBLK=64, double-buffered staging, defer-max (T13).
// ---------------------------------------------------------------------------
__global__ __launch_bounds__(256, 2) void flash_attn_mfma(
        const ushort* __restrict__ qkB,
        const ushort* __restrict__ Vt,
        ushort* __restrict__ attnB) {
    __shared__ ushort Kf[2][16 * 512];   // [buf][16 frags x 1024 B]
    __shared__ ushort Vf[2][16 * 512];

    const int b = blockIdx.x;              // 512
    const int half = b >> 8;
    const int rest = b & 255;
    const int h = rest >> 3;               // 0..31
    const int q8 = rest & 7;
    const int qi = half ? (15 - q8) : q8;  // 0..15, paired for balance
    const int kvh = h >> 2;

    const int tid = threadIdx.x;
    const int w = tid >> 6;
    const int l = tid & 63;
    const int l31 = l & 31;
    const int hf = l >> 5;

    const int qg = qi * 128 + w * 32 + l31;   // this lane's q row

    short8 qf[8];
    {
        const ushort* qrow = qkB + (size_t)qg * QKVN + h * HD + hf * 8;
#pragma unroll
        for (int kt = 0; kt < 8; kt++)
            qf[kt] = *(const short8*)(qrow + kt * 16);
    }

    f32x16 O[4];
#pragma unroll
    for (int dt = 0; dt < 4; dt++)
#pragma unroll
        for (int r = 0; r < 16; r++) O[dt][r] = 0.f;
    float mcur = -INFINITY, lcur = 0.f;

    const ushort* kbase = qkB + (size_t)l31 * QKVN + KV_OFF + kvh * HD + (2 * w) * 16 + hf * 8;
    const ushort* vbase = Vt + ((size_t)(kvh * 128 + w * 32 + l31)) * 2048 + hf * 8;

    auto ldsK = (__attribute__((address_space(3))) char*)&Kf[0][0];
    auto ldsV = (__attribute__((address_space(3))) char*)&Vf[0][0];

    const int nst = 2 * qi + 2;              // 64-key tiles
    const int mylast = (4 * qi + w) >> 1;    // last tile this wave computes

#define GLD(src, dst) __builtin_amdgcn_global_load_lds(                              \
        (const __attribute__((address_space(1))) void*)(src),                        \
        (__attribute__((address_space(3))) void*)(dst), 16, 0, 0)

#define AST64(j, bb)                                                                 \
    do {                                                                             \
        const ushort* kg0 = kbase + (size_t)(j) * 64 * QKVN;                         \
        const ushort* kg1 = kg0 + (size_t)32 * QKVN;                                 \
        GLD(kg0,      ldsK + (bb) * 16384 + (2 * w) * 1024);                         \
        GLD(kg0 + 16, ldsK + (bb) * 16384 + (2 * w + 1) * 1024);                     \
        GLD(kg1,      ldsK + (bb) * 16384 + (8 + 2 * w) * 1024);                     \
        GLD(kg1 + 16, ldsK + (bb) * 16384 + (8 + 2 * w + 1) * 1024);                 \
        const ushort* vg = vbase + (j) * 64;                                         \
        GLD(vg,       ldsV + (bb) * 16384 + (4 * w + 0) * 1024);                     \
        GLD(vg + 16,  ldsV + (bb) * 16384 + (4 * w + 1) * 1024);                     \
        GLD(vg + 32,  ldsV + (bb) * 16384 + (4 * w + 2) * 1024);                     \
        GLD(vg + 48,  ldsV + (bb) * 16384 + (4 * w + 3) * 1024);                     \
    } while (0)

    AST64(0, 0);   // prologue: stage tile 0 into buf 0

    for (int j = 0; j < nst; j++) {
        const int buf = j & 1;
        __builtin_amdgcn_s_barrier();            // all waves done computing j-1
        if (j + 1 < nst) {
            AST64(j + 1, buf ^ 1);
            asm volatile("s_waitcnt vmcnt(8)" ::: "memory");   // tile j's loads landed
        } else {
            asm volatile("s_waitcnt vmcnt(0)" ::: "memory");
        }
        __builtin_amdgcn_s_barrier();            // everyone's tile-j loads visible

        if (j <= mylast) {  // wave-uniform predicate (w-dependent)
            const ushort* Kb = &Kf[buf][0];
            const ushort* Vb = &Vf[buf][0];
            // ---- S^T = K · Q^T (two 32-key sub-tiles) ----
            f32x16 S0, S1;
#pragma unroll
            for (int r = 0; r < 16; r++) { S0[r] = 0.f; S1[r] = 0.f; }
            __builtin_amdgcn_s_setprio(1);
#pragma unroll
            for (int kt = 0; kt < 8; kt++) {
                short8 k0 = *(const short8*)(Kb + kt * 512 + l * 8);
                S0 = __builtin_amdgcn_mfma_f32_32x32x16_bf16(k0, qf[kt], S0, 0, 0, 0);
            }
#pragma unroll
            for (int kt = 0; kt < 8; kt++) {
                short8 k1 = *(const short8*)(Kb + (8 + kt) * 512 + l * 8);
                S1 = __builtin_amdgcn_mfma_f32_32x32x16_bf16(k1, qf[kt], S1, 0, 0, 0);
            }
            __builtin_amdgcn_s_setprio(0);

            if (j == mylast) {
                const int sb = j * 64 + 4 * hf;
#pragma unroll
                for (int r = 0; r < 16; r++) {
                    const int sg = sb + (r & 3) + 8 * (r >> 2);
                    if (sg > qg) S0[r] = -INFINITY;
                    if (sg + 32 > qg) S1[r] = -INFINITY;
                }
            }
            float rmax = S0[0];
#pragma unroll
            for (int r = 1; r < 16; r++) rmax = fmaxf(rmax, S0[r]);
#pragma unroll
            for (int r = 0; r < 16; r++) rmax = fmaxf(rmax, S1[r]);
            rmax = fmaxf(rmax, __shfl_xor(rmax, 32));

            // ---- defer-max (T13): skip rescale when max growth <= 8 ----
            const unsigned long long need = __ballot(rmax > mcur + 8.0f);
            float mnew, alpha;
            if (need == 0) { mnew = mcur; alpha = 1.0f; }
            else { mnew = fmaxf(mcur, rmax); alpha = __expf(mcur - mnew); }

            float rsum = 0.f;
#pragma unroll
            for (int r = 0; r < 16; r++) {
                S0[r] = __expf(S0[r] - mnew);
                rsum += S0[r];
            }
#pragma unroll
            for (int r = 0; r < 16; r++) {
                S1[r] = __expf(S1[r] - mnew);
                rsum += S1[r];
            }
            rsum += __shfl_xor(rsum, 32);
            lcur = lcur * alpha + rsum;
            mcur = mnew;

            if (need != 0) {
#pragma unroll
                for (int dt = 0; dt < 4; dt++)
#pragma unroll
                    for (int r = 0; r < 16; r++) O[dt][r] *= alpha;
            }

            // ---- build PV B-frags Pf[0..3] (ks 0..3 over 64 keys) ----
            short8 Pf[4];
            {
                unsigned pk[8], rk[8];
#pragma unroll
                for (int g = 0; g < 4; g++) {
                    pk[2 * g]     = (unsigned)f2bf(S0[4 * g])     | ((unsigned)f2bf(S0[4 * g + 1]) << 16);
                    pk[2 * g + 1] = (unsigned)f2bf(S0[4 * g + 2]) | ((unsigned)f2bf(S0[4 * g + 3]) << 16);
                }
#pragma unroll
                for (int i = 0; i < 8; i++) rk[i] = (unsigned)__shfl_xor((int)pk[i], 32);
#pragma unroll
                for (int kt2 = 0; kt2 < 2; kt2++) {
                    const int g = 2 * kt2 + hf;
                    union { unsigned u[4]; short8 s; } cvt;
                    cvt.u[0] = hf ? rk[2 * g]     : pk[2 * g];
                    cvt.u[1] = hf ? rk[2 * g + 1] : pk[2 * g + 1];
                    cvt.u[2] = hf ? pk[2 * g]     : rk[2 * g];
                    cvt.u[3] = hf ? pk[2 * g + 1] : rk[2 * g + 1];
                    Pf[kt2] = cvt.s;
                }
#pragma unroll
                for (int g = 0; g < 4; g++) {
                    pk[2 * g]     = (unsigned)f2bf(S1[4 * g])     | ((unsigned)f2bf(S1[4 * g + 1]) << 16);
                    pk[2 * g + 1] = (unsigned)f2bf(S1[4 * g + 2]) | ((unsigned)f2bf(S1[4 * g + 3]) << 16);
                }
#pragma unroll
                for (int i = 0; i < 8; i++) rk[i] = (unsigned)__shfl_xor((int)pk[i], 32);
#pragma unroll
                for (int kt2 = 0; kt2 < 2; kt2++) {
                    const int g = 2 * kt2 + hf;
                    union { unsigned u[4]; short8 s; } cvt;
                    cvt.u[0] = hf ? rk[2 * g]     : pk[2 * g];
                    cvt.u[1] = hf ? rk[2 * g + 1] : pk[2 * g + 1];
                    cvt.u[2] = hf ? pk[2 * g]     : rk[2 * g];
                    cvt.u[3] = hf ? pk[2 * g + 1] : rk[2 * g + 1];
                    Pf[2 + kt2] = cvt.s;
                }
            }

            // ---- O^T += V^T · P^T ----
            __builtin_amdgcn_s_setprio(1);
#pragma unroll
            for (int dt = 0; dt < 4; dt++)
#pragma unroll
                for (int ks = 0; ks < 4; ks++) {
                    short8 afV = *(const short8*)(Vb + (dt * 4 + ks) * 512 + l * 8);
                    O[dt] = __builtin_amdgcn_mfma_f32_32x32x16_bf16(afV, Pf[ks], O[dt], 0, 0, 0);
                }
            __builtin_amdgcn_s_setprio(0);
        }
    }
#undef AST64
#undef GLD

    const float inv = 1.0f / lcur;
    ushort* orow = attnB + (size_t)qg * HDIM + h * HD + 4 * hf;
#pragma unroll
    for (int dt = 0; dt < 4; dt++)
#pragma unroll
        for (int rg = 0; rg < 4; rg++) {
            ushort4 o;
            o.x = f2bf(O[dt][4 * rg + 0] * inv);
            o.y = f2bf(O[dt][4 * rg + 1] * inv);
            o.z = f2bf(O[dt][4 * rg + 2] * inv);
            o.w = f2bf(O[dt][4 * rg + 3] * inv);
            *(ushort4*)(orow + dt * 32 + 8 * rg) = o;
        }
}

// ---------------------------------------------------------------------------
// Fallback fp32 path — used only if workspace is too small.
// ---------------------------------------------------------------------------
__global__ __launch_bounds__(256) void rope_kernel(const int* __restrict__ pos,
                                                   float* __restrict__ qkv) {
    const int t = blockIdx.x;
    const int head = blockIdx.y * 4 + (threadIdx.x >> 6);
    const int d = threadIdx.x & 63;
    const float p = (float)pos[t];
    const float invf = exp2f(-(float)d * (19.931568569324174f / 64.0f));
    const float f = p * invf;
    const float c = cosf(f), s = sinf(f);
    float* base = qkv + (size_t)t * QKVN + head * HD;
    const float x1 = base[d];
    const float x2 = base[d + 64];
    base[d]      = x1 * c - x2 * s;
    base[d + 64] = x2 * c + x1 * s;
}

#define DOT4(acc, a, b) acc += (a).x*(b).x + (a).y*(b).y + (a).z*(b).z + (a).w*(b).w
#define FMA4(o, p, v) { (o).x += (p)*(v).x; (o).y += (p)*(v).y; (o).z += (p)*(v).z; (o).w += (p)*(v).w; }

__global__ __launch_bounds__(256, 2) void flash_attn_f32(const float* __restrict__ qkv,
                                                         float* __restrict__ out) {
    __shared__ float Qs[64 * 132];
    __shared__ float KVs[32 * 132];
    __shared__ float Ps[64 * 34];
    const int b = blockIdx.x;
    const int half = (b >> 9) & 1;
    const int rest = b & 511;
    const int h = rest >> 4;
    const int qlo = rest & 15;
    const int qi = half ? (31 - qlo) : qlo;
    const int kvh = h >> 2;
    const int tid = threadIdx.x;
    const int tx = tid & 7;
    const int ty = tid >> 3;
    {
        const float* qbase = qkv + (size_t)(qi * 64) * QKVN + h * HD;
#pragma unroll
        for (int r = 0; r < 8; r++) {
            int idx = r * 256 + tid;
            int qrow = idx >> 5;
            int d = (idx & 31) * 4;
            float4 v = *(const float4*)(qbase + (size_t)qrow * QKVN + d);
            v.x *= SCALE; v.y *= SCALE; v.z *= SCALE; v.w *= SCALE;
            *(float4*)(Qs + qrow * 132 + d) = v;
        }
    }
    float m[2], lsm[2];
    float4 O[2][4];
#pragma unroll
    for (int i = 0; i < 2; i++) {
        m[i] = -INFINITY; lsm[i] = 0.f;
#pragma unroll
        for (int jj = 0; jj < 4; jj++) O[i][jj] = make_float4(0.f, 0.f, 0.f, 0.f);
    }
    const float* kbase = qkv + KV_OFF + kvh * HD;
    const float* vbase = qkv + V_OFF + kvh * HD;
    const int qg0 = qi * 64 + ty;
    const int nst = 2 * qi + 2;
    for (int st = 0; st < nst; st++) {
        __syncthreads();
#pragma unroll
        for (int r = 0; r < 4; r++) {
            int idx = r * 256 + tid;
            int srow = idx >> 5;
            int d = (idx & 31) * 4;
            *(float4*)(KVs + srow * 132 + d) =
                *(const float4*)(kbase + (size_t)(st * 32 + srow) * QKVN + d);
        }
        __syncthreads();
        float S[2][4];
#pragma unroll
        for (int i = 0; i < 2; i++)
#pragma unroll
            for (int j = 0; j < 4; j++) S[i][j] = 0.f;
#pragma unroll 4
        for (int kk = 0; kk < HD; kk += 4) {
            float4 q0 = *(const float4*)(Qs + ty * 132 + kk);
            float4 q1 = *(const float4*)(Qs + (ty + 32) * 132 + kk);
            float4 k0 = *(const float4*)(KVs + tx * 132 + kk);
            float4 k1 = *(const float4*)(KVs + (tx + 8) * 132 + kk);
            float4 k2 = *(const float4*)(KVs + (tx + 16) * 132 + kk);
            float4 k3 = *(const float4*)(KVs + (tx + 24) * 132 + kk);
            DOT4(S[0][0], q0, k0); DOT4(S[0][1], q0, k1);
            DOT4(S[0][2], q0, k2); DOT4(S[0][3], q0, k3);
            DOT4(S[1][0], q1, k0); DOT4(S[1][1], q1, k1);
            DOT4(S[1][2], q1, k2); DOT4(S[1][3], q1, k3);
        }
        const int sg0 = st * 32 + tx;
        float alpha[2];
#pragma unroll
        for (int i = 0; i < 2; i++) {
            const int qg = qg0 + 32 * i;
            float rmax = -INFINITY;
#pragma unroll
            for (int j = 0; j < 4; j++) {
                if (sg0 + 8 * j > qg) S[i][j] = -INFINITY;
                rmax = fmaxf(rmax, S[i][j]);
            }
#pragma unroll
            for (int off = 1; off < 8; off <<= 1)
                rmax = fmaxf(rmax, __shfl_xor(rmax, off));
            const float mnew = fmaxf(m[i], rmax);
            alpha[i] = __expf(m[i] - mnew);
            float rsum = 0.f;
#pragma unroll
            for (int j = 0; j < 4; j++) {
                S[i][j] = __expf(S[i][j] - mnew);
                rsum += S[i][j];
            }
#pragma unroll
            for (int off = 1; off < 8; off <<= 1)
                rsum += __shfl_xor(rsum, off);
            lsm[i] = lsm[i] * alpha[i] + rsum;
            m[i] = mnew;
        }
#pragma unroll
        for (int i = 0; i < 2; i++)
#pragma unroll
            for (int j = 0; j < 4; j++)
                Ps[(ty + 32 * i) * 34 + tx + 8 * j] = S[i][j];
        __syncthreads();
#pragma unroll
        for (int r = 0; r < 4; r++) {
            int idx = r * 256 + tid;
            int srow = idx >> 5;
            int d = (idx & 31) * 4;
            *(float4*)(KVs + srow * 132 + d) =
                *(const float4*)(vbase + (size_t)(st * 32 + srow) * QKVN + d);
        }
        __syncthreads();
#pragma unroll
        for (int i = 0; i < 2; i++) {
            const float a = alpha[i];
#pragma unroll
            for (int jj = 0; jj < 4; jj++) {
                O[i][jj].x *= a; O[i][jj].y *= a; O[i][jj].z *= a; O[i][jj].w *= a;
            }
        }
#pragma unroll 4
        for (int s = 0; s < 32; s++) {
            float p0 = Ps[ty * 34 + s];
            float p1 = Ps[(ty + 32) * 34 + s];
            const float* vr = KVs + s * 132 + 4 * tx;
            float4 v0 = *(const float4*)(vr);
            float4 v1 = *(const float4*)(vr + 32);
            float4 v2 = *(const float4*)(vr + 64);
            float4 v3 = *(const float4*)(vr + 96);
            FMA4(O[0][0], p0, v0); FMA4(O[0][1], p0, v1);
            FMA4(O[0][2], p0, v2); FMA4(O[0][3], p0, v3);
            FMA4(O[1][0], p1, v0); FMA4(O[1][1], p1, v1);
            FMA4(O[1][2], p1, v2); FMA4(O[1][3], p1, v3);
        }
    }
#pragma unroll
    for (int i = 0; i < 2; i++) {
        const float inv = 1.0f / lsm[i];
        float* orow = out + (size_t)(qi * 64 + ty + 32 * i) * HDIM + h * HD + 4 * tx;
#pragma unroll
        for (int jj = 0; jj < 4; jj++) {
            float4 wv = O[i][jj];
            wv.x *= inv; wv.y *= inv; wv.z *= inv; wv.w *= inv;
            *(float4*)(orow + 32 * jj) = wv;
        }
    }
}

template <int N_, int K_>
__global__ __launch_bounds__(256) void sgemm(const float* __restrict__ A,
                                             const float* __restrict__ B,
                                             float* __restrict__ C) {
    __shared__ float As[8][128];
    __shared__ float Bs[8][128];
    const int tid = threadIdx.x;
    const int bm = blockIdx.y * 128;
    const int bn = blockIdx.x * 128;
    const int tx = tid & 15;
    const int ty = tid >> 4;
    const int lm = tid >> 1;
    const int lkq = (tid & 1) * 4;
    const int lr = tid >> 5;
    const int lnq = (tid & 31) * 4;
    float acc[8][8];
#pragma unroll
    for (int i = 0; i < 8; i++)
#pragma unroll
        for (int j = 0; j < 8; j++) acc[i][j] = 0.f;
    const float* Aptr = A + (size_t)(bm + lm) * K_ + lkq;
    const float* Bptr = B + (size_t)lr * N_ + bn + lnq;
    for (int k0 = 0; k0 < K_; k0 += 8) {
        float4 av = *(const float4*)Aptr;
        float4 bv = *(const float4*)Bptr;
        __syncthreads();
        As[lkq + 0][lm] = av.x;
        As[lkq + 1][lm] = av.y;
        As[lkq + 2][lm] = av.z;
        As[lkq + 3][lm] = av.w;
        *(float4*)&Bs[lr][lnq] = bv;
        __syncthreads();
        Aptr += 8;
        Bptr += (size_t)8 * N_;
#pragma unroll
        for (int kk = 0; kk < 8; kk++) {
            float4 a0 = *(const float4*)&As[kk][ty * 4];
            float4 a1 = *(const float4*)&As[kk][64 + ty * 4];
            float4 b0 = *(const float4*)&Bs[kk][tx * 4];
            float4 b1 = *(const float4*)&Bs[kk][64 + tx * 4];
            float a[8] = {a0.x, a0.y, a0.z, a0.w, a1.x, a1.y, a1.z, a1.w};
            float bb[8] = {b0.x, b0.y, b0.z, b0.w, b1.x, b1.y, b1.z, b1.w};
#pragma unroll
            for (int i = 0; i < 8; i++)
#pragma unroll
                for (int j = 0; j < 8; j++) acc[i][j] += a[i] * bb[j];
        }
    }
#pragma unroll
    for (int i = 0; i < 8; i++) {
        int row = bm + ((i < 4) ? (ty * 4 + i) : (64 + ty * 4 + i - 4));
        float4 c0 = {acc[i][0], acc[i][1], acc[i][2], acc[i][3]};
        float4 c1 = {acc[i][4], acc[i][5], acc[i][6], acc[i][7]};
        *(float4*)&C[(size_t)row * N_ + bn + tx * 4] = c0;
        *(float4*)&C[(size_t)row * N_ + bn + 64 + tx * 4] = c1;
    }
}

// ---------------------------------------------------------------------------
extern "C" void kernel_launch(void* const* d_in, const int* in_sizes, int n_in,
                              void* d_out, int out_size, void* d_ws, size_t ws_size,
                              hipStream_t stream) {
    const int*   positions = (const int*)d_in[0];
    const float* hidden    = (const float*)d_in[1];
    const float* Wqkv      = (const float*)d_in[2];
    const float* Wo        = (const float*)d_in[3];
    float* out = (float*)d_out;

    char* ws = (char*)d_ws;
    // fast-path layout (fp32 qkv eliminated; Pk overlays dead WqkvT):
    ushort* qkB   = (ushort*)ws;                    // [0, 25165824)
    ushort* Vt    = (ushort*)(ws + 25165824);       // [25165824, 29360128)
    ushort* attnB = (ushort*)(ws + 29360128);       // [29360128, 46137344)
    float*  Pk    = (float*)(ws + 46137344);        // [46137344, 79691776) overlays dead WqkvT tail
    ushort* WqkvT = (ushort*)(ws + 50331648);       // [50331648, 100663296) dead after gemm1
    ushort* WoT   = (ushort*)(ws + 100663296);      // [100663296, 134217728)
    ushort* hA    = (ushort*)(ws + 134217728);      // [134217728, 150994944) dead after gemm1
    const size_t NEEDED = 163577856;

    if (ws_size >= NEEDED) {
        cast_bf16<<<dim3((T_TOK * HDIM) / 1024), 256, 0, stream>>>(hidden, hA);
        transpose_cast<HDIM, QKVN><<<dim3(QKVN / 64, HDIM / 32), 256, 0, stream>>>(Wqkv, WqkvT);
        transpose_cast<HDIM, HDIM><<<dim3(HDIM / 64, HDIM / 32), 256, 0, stream>>>(Wo, WoT);
        gemm_bf16_8ph<QKVN, HDIM, HDIM, 1>
            <<<dim3((T_TOK / 256) * (QKVN / 256), 1), 512, 0, stream>>>(
                hA, WqkvT, nullptr, nullptr, positions, qkB, Vt);
        flash_attn_mfma<<<dim3(512), 256, 0, stream>>>(qkB, Vt, attnB);
        gemm_bf16_8ph<HDIM, HDIM, HDIM / 2, 0>
            <<<dim3((T_TOK / 256) * (HDIM / 256), 2), 512, 0, stream>>>(
                attnB, WoT, out, Pk, nullptr, nullptr, nullptr);
        add_f32<<<dim3((T_TOK * HDIM) / 1024), 256, 0, stream>>>(out, Pk);
    } else {
        float* qkv  = (float*)ws;
        float* attn = qkv + (size_t)T_TOK * QKVN;
        sgemm<QKVN, HDIM><<<dim3(QKVN / 128, T_TOK / 128), 256, 0, stream>>>(hidden, Wqkv, qkv);
        rope_kernel<<<dim3(T_TOK, 10), 256, 0, stream>>>(positions, qkv);
        flash_attn_f32<<<dim3(1024), 256, 0, stream>>>(qkv, attn);
        sgemm<HDIM, HDIM><<<dim3(HDIM / 128, T_TOK / 128), 256, 0, stream>>>(attn, Wo, out);
    }
}

// Round 6
// 588.669 us; speedup vs baseline: 1.2510x; 1.0265x over previous
//
#include <hip/hip_runtime.h>
#include <math.h>

#define T_TOK 2048
#define HDIM  4096
#define QKVN  6144
#define NHEADS 32
#define HD    128
#define KV_OFF 4096
#define V_OFF  5120
#define SCALE 0.08838834764831843f

typedef __attribute__((ext_vector_type(8))) short short8;
typedef __attribute__((ext_vector_type(4))) float f32x4;
typedef __attribute__((ext_vector_type(16))) float f32x16;

__device__ __forceinline__ ushort f2bf(float f) {
    union { float f; unsigned u; } v; v.f = f;
    unsigned r = v.u + 0x7FFFu + ((v.u >> 16) & 1u);   // RNE
    return (ushort)(r >> 16);
}

// ---------------------------------------------------------------------------
// 256x256 8-phase bf16 MFMA GEMM (R1/R4 schedule). C = A[M,:]*B^T[N,:].
// MODE 0: plain fp32 C write. MODE 1: fused rope/VT epilogue (no fp32 C).
// ---------------------------------------------------------------------------
template <int N_, int LDK, int KC, int MODE>
__global__ __launch_bounds__(512, 2) void gemm_bf16_8ph(const ushort* __restrict__ A,
                                                        const ushort* __restrict__ B,
                                                        float* __restrict__ C0,
                                                        float* __restrict__ C1,
                                                        const int* __restrict__ pos,
                                                        ushort* __restrict__ qkB,
                                                        ushort* __restrict__ Vt) {
    __shared__ __attribute__((aligned(16))) ushort As[2][2][8192];  // [buf][half][128*64]
    __shared__ __attribute__((aligned(16))) ushort Bs[2][2][8192];

    constexpr int NT = KC / 64;
    constexpr int NBN = N_ / 256;

    const int kz = blockIdx.y;

    const int nwgx = (int)gridDim.x;
    const int bid = (int)blockIdx.x;
    const int swz = (nwgx & 7) ? bid : ((bid & 7) * (nwgx >> 3) + (bid >> 3));  // XCD swizzle
    const int bm = (swz / NBN) * 256;
    const int bn = (swz % NBN) * 256;

    const int tid = (int)threadIdx.x;
    const int w = tid >> 6;           // 0..7
    const int l = tid & 63;
    const int hfa = w >> 2;           // A half used by this wave
    const int hfb = (w & 3) >> 1;     // B half used by this wave
    const int wbr64 = (w & 1) * 4096; // row-offset*64 within B half

    // ds-read addressing: element idx = frag*1024 + (l&15)*64 + colswz
    const int arc = (l & 15) * 64;
    const int ac0 = ((((l >> 4) << 4)) ^ ((l & 7) << 4)) >> 1;
    const int ac1 = (((1 << 6) | ((l >> 4) << 4)) ^ ((l & 7) << 4)) >> 1;

    // stage source addressing (inverse swizzle folded into per-lane col)
    const int grow = w * 8 + (l >> 3);            // 0..63
    const int gcol = ((l & 7) ^ (l >> 3)) * 8;    // element col within 64
    const ushort* Ag = A + (size_t)kz * KC + (size_t)(bm + grow) * LDK + gcol;
    const ushort* Bg = B + (size_t)kz * KC + (size_t)(bn + grow) * LDK + gcol;

    auto ldsA = (__attribute__((address_space(3))) char*)&As[0][0][0];
    auto ldsB = (__attribute__((address_space(3))) char*)&Bs[0][0][0];
    const int wsl = w * 1024;

#define STG2(ldsbase, gsrc, bufi, hfi, kt)                                                              \
    do {                                                                                                \
        __builtin_amdgcn_global_load_lds(                                                               \
            (const __attribute__((address_space(1))) void*)((gsrc) + (size_t)((hfi) * 128) * LDK + (kt) * 64),       \
            (__attribute__((address_space(3))) void*)((ldsbase) + (bufi) * 32768 + (hfi) * 16384 + wsl), 16, 0, 0);  \
        __builtin_amdgcn_global_load_lds(                                                               \
            (const __attribute__((address_space(1))) void*)((gsrc) + (size_t)((hfi) * 128 + 64) * LDK + (kt) * 64),  \
            (__attribute__((address_space(3))) void*)((ldsbase) + (bufi) * 32768 + (hfi) * 16384 + 8192 + wsl), 16, 0, 0); \
    } while (0)

    // prologue: tile0 fully, then tile1 (B-h0,B-h1,A-h0)
    STG2(ldsB, Bg, 0, 0, 0);
    STG2(ldsB, Bg, 0, 1, 0);
    STG2(ldsA, Ag, 0, 0, 0);
    STG2(ldsA, Ag, 0, 1, 0);
    STG2(ldsB, Bg, 1, 0, 1);
    STG2(ldsB, Bg, 1, 1, 1);
    STG2(ldsA, Ag, 1, 0, 1);
    asm volatile("s_waitcnt vmcnt(6)" ::: "memory");   // tile0's 8 loads done
    __builtin_amdgcn_s_barrier();

    f32x4 acc[8][4];
#pragma unroll
    for (int i = 0; i < 8; i++)
#pragma unroll
        for (int j = 0; j < 4; j++) acc[i][j] = (f32x4){0.f, 0.f, 0.f, 0.f};

    short8 a0[4][2], a1[4][2], bq[4][2];

    int buf = 0;
    for (int t = 0; t < NT; ++t) {
        const int nb = buf ^ 1;
        const ushort* Abuf = &As[buf][hfa][0];
        const ushort* Bbuf = &Bs[buf][hfb][0] + wbr64;

        // ---- phase 1: read a0(8)+bq(8); stage A-h1(t+1); MFMA acc[0..3][0..1] ----
#pragma unroll
        for (int fi = 0; fi < 4; fi++) {
            a0[fi][0] = *(const short8*)(Abuf + fi * 1024 + arc + ac0);
            a0[fi][1] = *(const short8*)(Abuf + fi * 1024 + arc + ac1);
        }
#pragma unroll
        for (int fj = 0; fj < 4; fj++) {
            bq[fj][0] = *(const short8*)(Bbuf + fj * 1024 + arc + ac0);
            bq[fj][1] = *(const short8*)(Bbuf + fj * 1024 + arc + ac1);
        }
        if (t + 1 < NT) STG2(ldsA, Ag, nb, 1, t + 1);
        __builtin_amdgcn_s_barrier();
        __builtin_amdgcn_s_setprio(1);
#pragma unroll
        for (int fi = 0; fi < 4; fi++)
#pragma unroll
            for (int fj = 0; fj < 2; fj++)
#pragma unroll
                for (int s = 0; s < 2; s++)
                    acc[fi][fj] = __builtin_amdgcn_mfma_f32_16x16x32_bf16(a0[fi][s], bq[fj][s], acc[fi][fj], 0, 0, 0);
        __builtin_amdgcn_s_setprio(0);
        __builtin_amdgcn_s_barrier();

        // ---- phase 2: stage B-h0(t+2); MFMA acc[0..3][2..3] ----
        if (t + 2 < NT) STG2(ldsB, Bg, buf, 0, t + 2);
        __builtin_amdgcn_s_barrier();
        __builtin_amdgcn_s_setprio(1);
#pragma unroll
        for (int fi = 0; fi < 4; fi++)
#pragma unroll
            for (int fj = 2; fj < 4; fj++)
#pragma unroll
                for (int s = 0; s < 2; s++)
                    acc[fi][fj] = __builtin_amdgcn_mfma_f32_16x16x32_bf16(a0[fi][s], bq[fj][s], acc[fi][fj], 0, 0, 0);
        __builtin_amdgcn_s_setprio(0);
        __builtin_amdgcn_s_barrier();

        // ---- phase 3: read a1(8); stage B-h1(t+2); MFMA acc[4..7][2..3] ----
#pragma unroll
        for (int fi = 0; fi < 4; fi++) {
            a1[fi][0] = *(const short8*)(Abuf + (fi + 4) * 1024 + arc + ac0);
            a1[fi][1] = *(const short8*)(Abuf + (fi + 4) * 1024 + arc + ac1);
        }
        if (t + 2 < NT) STG2(ldsB, Bg, buf, 1, t + 2);
        __builtin_amdgcn_s_barrier();
        __builtin_amdgcn_s_setprio(1);
#pragma unroll
        for (int fi = 0; fi < 4; fi++)
#pragma unroll
            for (int fj = 2; fj < 4; fj++)
#pragma unroll
                for (int s = 0; s < 2; s++)
                    acc[fi + 4][fj] = __builtin_amdgcn_mfma_f32_16x16x32_bf16(a1[fi][s], bq[fj][s], acc[fi + 4][fj], 0, 0, 0);
        __builtin_amdgcn_s_setprio(0);
        __builtin_amdgcn_s_barrier();

        // ---- phase 4: stage A-h0(t+2); vmcnt(6); MFMA acc[4..7][0..1] ----
        if (t + 2 < NT) {
            STG2(ldsA, Ag, buf, 0, t + 2);
            asm volatile("s_waitcnt vmcnt(6)" ::: "memory");   // tile t+1 fully landed
        } else {
            asm volatile("s_waitcnt vmcnt(0)" ::: "memory");   // tail drain
        }
        __builtin_amdgcn_s_barrier();
        __builtin_amdgcn_s_setprio(1);
#pragma unroll
        for (int fi = 0; fi < 4; fi++)
#pragma unroll
            for (int fj = 0; fj < 2; fj++)
#pragma unroll
                for (int s = 0; s < 2; s++)
                    acc[fi + 4][fj] = __builtin_amdgcn_mfma_f32_16x16x32_bf16(a1[fi][s], bq[fj][s], acc[fi + 4][fj], 0, 0, 0);
        __builtin_amdgcn_s_setprio(0);
        __builtin_amdgcn_s_barrier();

        buf = nb;
    }
#undef STG2

    if constexpr (MODE == 0) {
        float* __restrict__ C = kz ? C1 : C0;
        const int cn = bn + (w & 3) * 64 + (l & 15);
        const int rm = bm + hfa * 128 + ((l >> 4) << 2);
#pragma unroll
        for (int fi = 0; fi < 8; fi++)
#pragma unroll
            for (int fj = 0; fj < 4; fj++)
#pragma unroll
                for (int r = 0; r < 4; r++)
                    C[(size_t)(rm + 16 * fi + r) * N_ + cn + 16 * fj] = acc[fi][fj][r];
    } else {
        // ---- fused qkv epilogue ----
        float* Ls = (float*)&As[0][0][0];   // strip 32 x 260 fp32, reuses dead LDS
        const bool isV = (bn >= V_OFF);
        const int q = w & 3;
        const int r4 = (l >> 4) << 2;
#pragma unroll
        for (int fi = 0; fi < 8; fi++) {
#pragma unroll
            for (int fj = 0; fj < 4; fj++)
#pragma unroll
                for (int r = 0; r < 4; r++)
                    Ls[(hfa * 16 + r4 + r) * 260 + q * 64 + (l & 15) + 16 * fj] = acc[fi][fj][r];
            __builtin_amdgcn_s_barrier();
            if (!isV) {
                const int trow = bm + hfa * 128 + 16 * fi + r4;
#pragma unroll
                for (int r = 0; r < 4; r++) {
                    const int t = trow + r;
                    const float p = (float)pos[t];
#pragma unroll
                    for (int fj = 0; fj < 4; fj++) {
                        const int cr = q * 64 + (l & 15) + 16 * fj;
                        const int dd = cr & 127;
                        const int d64 = dd & 63;
                        const float own = acc[fi][fj][r];
                        const float prt = Ls[(hfa * 16 + r4 + r) * 260 + (cr ^ 64)];
                        const float invf = exp2f(-(float)d64 * (19.931568569324174f / 64.0f));
                        const float ang = p * invf;
                        const float cf = __cosf(ang), sf = __sinf(ang);
                        const float o = (dd < 64) ? (own * cf - prt * sf) : (own * cf + prt * sf);
                        const float sc = (bn + cr < KV_OFF) ? SCALE : 1.0f;
                        qkB[(size_t)t * QKVN + bn + cr] = f2bf(o * sc);
                    }
                }
            } else {
                const int vcr = tid >> 1;
                const int hh = tid & 1;
                union { ushort u[16]; short8 s[2]; } tmp;
#pragma unroll
                for (int rr = 0; rr < 16; rr++)
                    tmp.u[rr] = f2bf(Ls[(hh * 16 + rr) * 260 + vcr]);
                ushort* dst = Vt + (size_t)(bn - V_OFF + vcr) * 2048 + bm + hh * 128 + 16 * fi;
                *(short8*)dst = tmp.s[0];
                *(short8*)(dst + 8) = tmp.s[1];
            }
            __builtin_amdgcn_s_barrier();
        }
    }
}

// ---------------------------------------------------------------------------
// 256x128 bf16 MFMA GEMM, full-K, triple-buffered LDS (144 KiB), 2 phases/tile.
// Grid = (M/256)*(N/128) = 256 blocks -> full CU coverage, no split-K/add.
// Staging 2 tiles ahead into buffer (t+2)%3 — WAR-safe by construction.
// vmcnt(6) once per tile at phB retires exactly tile t+1 (queue 12 -> 6).
// ---------------------------------------------------------------------------
template <int N_, int LDK, int KC>
__global__ __launch_bounds__(512, 2) void gemm_bf16_n128(const ushort* __restrict__ A,
                                                         const ushort* __restrict__ B,
                                                         float* __restrict__ C) {
    __shared__ __attribute__((aligned(16))) ushort As[3][2][8192];  // 96 KiB
    __shared__ __attribute__((aligned(16))) ushort Bs[3][8192];     // 48 KiB

    constexpr int NT = KC / 64;
    constexpr int NBN = N_ / 128;

    const int nwgx = (int)gridDim.x;
    const int bid = (int)blockIdx.x;
    const int swz = (nwgx & 7) ? bid : ((bid & 7) * (nwgx >> 3) + (bid >> 3));
    const int bm = (swz / NBN) * 256;
    const int bn = (swz % NBN) * 128;

    const int tid = (int)threadIdx.x;
    const int w = tid >> 6;
    const int l = tid & 63;
    const int hfa = w >> 2;            // A half (128 rows)
    const int wq = w & 3;              // B quarter (32 rows)

    const int arc = (l & 15) * 64;
    const int ac0 = ((((l >> 4) << 4)) ^ ((l & 7) << 4)) >> 1;
    const int ac1 = (((1 << 6) | ((l >> 4) << 4)) ^ ((l & 7) << 4)) >> 1;

    const int grow = w * 8 + (l >> 3);
    const int gcol = ((l & 7) ^ (l >> 3)) * 8;
    const ushort* Ag = A + (size_t)(bm + grow) * LDK + gcol;
    const ushort* Bg = B + (size_t)(bn + grow) * LDK + gcol;

    auto ldsA = (__attribute__((address_space(3))) char*)&As[0][0][0];
    auto ldsBs = (__attribute__((address_space(3))) char*)&Bs[0][0];
    const int wsl = w * 1024;

#define GLD16(src, dst) __builtin_amdgcn_global_load_lds(                            \
        (const __attribute__((address_space(1))) void*)(src),                        \
        (__attribute__((address_space(3))) void*)(dst), 16, 0, 0)

#define STGA2(bufi, hfi, kt)                                                          \
    do {                                                                              \
        GLD16(Ag + (size_t)((hfi) * 128) * LDK + (kt) * 64,                           \
              ldsA + (bufi) * 32768 + (hfi) * 16384 + wsl);                           \
        GLD16(Ag + (size_t)((hfi) * 128 + 64) * LDK + (kt) * 64,                      \
              ldsA + (bufi) * 32768 + (hfi) * 16384 + 8192 + wsl);                    \
    } while (0)

#define STGB2(bufi, kt)                                                               \
    do {                                                                              \
        GLD16(Bg + (kt) * 64,                ldsBs + (bufi) * 16384 + wsl);           \
        GLD16(Bg + (size_t)64 * LDK + (kt) * 64, ldsBs + (bufi) * 16384 + 8192 + wsl);\
    } while (0)

    // prologue: tile0 {B, A-h0, A-h1}; tile1 {A-h1, B, A-h0}
    STGB2(0, 0);
    STGA2(0, 0, 0);
    STGA2(0, 1, 0);
    STGA2(1, 1, 1);
    STGB2(1, 1);
    STGA2(1, 0, 1);
    asm volatile("s_waitcnt vmcnt(6)" ::: "memory");   // tile0's 6 loads done
    __builtin_amdgcn_s_barrier();

    f32x4 acc[8][2];
#pragma unroll
    for (int i = 0; i < 8; i++)
#pragma unroll
        for (int j = 0; j < 2; j++) acc[i][j] = (f32x4){0.f, 0.f, 0.f, 0.f};

    short8 a0[4][2], a1[4][2], bq[2][2];

    int b0 = 0;
    for (int t = 0; t < NT; ++t) {
        const int b2 = (b0 >= 1) ? (b0 - 1) : 2;   // (t+2)%3
        const ushort* Abuf = &As[b0][hfa][0];
        const ushort* Bbuf = &Bs[b0][0] + wq * 2048;

        // ---- phase A: read a0(8)+bq(4); stage A-h1(t+2); MFMA acc[0..3][0..1] ----
#pragma unroll
        for (int fi = 0; fi < 4; fi++) {
            a0[fi][0] = *(const short8*)(Abuf + fi * 1024 + arc + ac0);
            a0[fi][1] = *(const short8*)(Abuf + fi * 1024 + arc + ac1);
        }
#pragma unroll
        for (int fj = 0; fj < 2; fj++) {
            bq[fj][0] = *(const short8*)(Bbuf + fj * 1024 + arc + ac0);
            bq[fj][1] = *(const short8*)(Bbuf + fj * 1024 + arc + ac1);
        }
        if (t + 2 < NT) STGA2(b2, 1, t + 2);
        __builtin_amdgcn_s_barrier();
        __builtin_amdgcn_s_setprio(1);
#pragma unroll
        for (int fi = 0; fi < 4; fi++)
#pragma unroll
            for (int fj = 0; fj < 2; fj++)
#pragma unroll
                for (int s = 0; s < 2; s++)
                    acc[fi][fj] = __builtin_amdgcn_mfma_f32_16x16x32_bf16(a0[fi][s], bq[fj][s], acc[fi][fj], 0, 0, 0);
        __builtin_amdgcn_s_setprio(0);
        __builtin_amdgcn_s_barrier();

        // ---- phase B: read a1(8); stage B(t+2)+A-h0(t+2); vmcnt(6); MFMA acc[4..7][0..1] ----
#pragma unroll
        for (int fi = 0; fi < 4; fi++) {
            a1[fi][0] = *(const short8*)(Abuf + (fi + 4) * 1024 + arc + ac0);
            a1[fi][1] = *(const short8*)(Abuf + (fi + 4) * 1024 + arc + ac1);
        }
        if (t + 2 < NT) {
            STGB2(b2, t + 2);
            STGA2(b2, 0, t + 2);
            asm volatile("s_waitcnt vmcnt(6)" ::: "memory");   // tile t+1 fully landed
        } else {
            asm volatile("s_waitcnt vmcnt(0)" ::: "memory");
        }
        __builtin_amdgcn_s_barrier();
        __builtin_amdgcn_s_setprio(1);
#pragma unroll
        for (int fi = 0; fi < 4; fi++)
#pragma unroll
            for (int fj = 0; fj < 2; fj++)
#pragma unroll
                for (int s = 0; s < 2; s++)
                    acc[fi + 4][fj] = __builtin_amdgcn_mfma_f32_16x16x32_bf16(a1[fi][s], bq[fj][s], acc[fi + 4][fj], 0, 0, 0);
        __builtin_amdgcn_s_setprio(0);
        __builtin_amdgcn_s_barrier();

        b0 = (b0 + 1 == 3) ? 0 : (b0 + 1);
    }
#undef STGA2
#undef STGB2
#undef GLD16

    const int cn = bn + wq * 32 + (l & 15);
    const int rm = bm + hfa * 128 + ((l >> 4) << 2);
#pragma unroll
    for (int fi = 0; fi < 8; fi++)
#pragma unroll
        for (int fj = 0; fj < 2; fj++)
#pragma unroll
            for (int r = 0; r < 4; r++)
                C[(size_t)(rm + 16 * fi + r) * N_ + cn + 16 * fj] = acc[fi][fj][r];
}

// ---------------------------------------------------------------------------
__global__ __launch_bounds__(256) void cast_bf16(const float* __restrict__ in,
                                                 ushort* __restrict__ outp) {
    const int i = (blockIdx.x * 256 + threadIdx.x) * 4;
    float4 v = *(const float4*)(in + i);
    ushort4 o = {f2bf(v.x), f2bf(v.y), f2bf(v.z), f2bf(v.w)};
    *(ushort4*)(outp + i) = o;
}

// ---------------------------------------------------------------------------
// 64x64 transpose+cast, short8 (16B) vectorized stores, 2 stores/thread.
// ---------------------------------------------------------------------------
template <int K_, int N_>
__global__ __launch_bounds__(256) void transpose_cast(const float* __restrict__ W,
                                                      ushort* __restrict__ WT) {
    __shared__ float T[64][65];
    const int k0 = blockIdx.y * 64;
    const int n0 = blockIdx.x * 64;
    const int x = threadIdx.x & 63;
    const int y = threadIdx.x >> 6;
#pragma unroll
    for (int p = 0; p < 16; p++) {
        const int kk = p * 4 + y;
        T[kk][x] = W[(size_t)(k0 + kk) * N_ + n0 + x];
    }
    __syncthreads();
    const int nl = threadIdx.x >> 2;         // 0..63
    const int kc = (threadIdx.x & 3) * 16;   // k chunk base
    union { ushort u[16]; short8 s[2]; } tmp;
#pragma unroll
    for (int i = 0; i < 16; i++) tmp.u[i] = f2bf(T[kc + i][nl]);
    ushort* dst = &WT[(size_t)(n0 + nl) * K_ + k0 + kc];
    *(short8*)dst = tmp.s[0];
    *(short8*)(dst + 8) = tmp.s[1];
}

// ---------------------------------------------------------------------------
// MFMA flash attention, KVBLK=64, double-buffered staging, defer-max (T13).
// ---------------------------------------------------------------------------
__global__ __launch_bounds__(256, 2) void flash_attn_mfma(
        const ushort* __restrict__ qkB,
        const ushort* __restrict__ Vt,
        ushort* __restrict__ attnB) {
    __shared__ ushort Kf[2][16 * 512];   // [buf][16 frags x 1024 B]
    __shared__ ushort Vf[2][16 * 512];

    const int b = blockIdx.x;              // 512
    const int half = b >> 8;
    const int rest = b & 255;
    const int h = rest >> 3;               // 0..31
    const int q8 = rest & 7;
    const int qi = half ? (15 - q8) : q8;  // 0..15, paired for balance
    const int kvh = h >> 2;

    const int tid = threadIdx.x;
    const int w = tid >> 6;
    const int l = tid & 63;
    const int l31 = l & 31;
    const int hf = l >> 5;

    const int qg = qi * 128 + w * 32 + l31;   // this lane's q row

    short8 qf[8];
    {
        const ushort* qrow = qkB + (size_t)qg * QKVN + h * HD + hf * 8;
#pragma unroll
        for (int kt = 0; kt < 8; kt++)
            qf[kt] = *(const short8*)(qrow + kt * 16);
    }

    f32x16 O[4];
#pragma unroll
    for (int dt = 0; dt < 4; dt++)
#pragma unroll
        for (int r = 0; r < 16; r++) O[dt][r] = 0.f;
    float mcur = -INFINITY, lcur = 0.f;

    const ushort* kbase = qkB + (size_t)l31 * QKVN + KV_OFF + kvh * HD + (2 * w) * 16 + hf * 8;
    const ushort* vbase = Vt + ((size_t)(kvh * 128 + w * 32 + l31)) * 2048 + hf * 8;

    auto ldsK = (__attribute__((address_space(3))) char*)&Kf[0][0];
    auto ldsV = (__attribute__((address_space(3))) char*)&Vf[0][0];

    const int nst = 2 * qi + 2;              // 64-key tiles
    const int mylast = (4 * qi + w) >> 1;    // last tile this wave computes

#define GLD(src, dst) __builtin_amdgcn_global_load_lds(                              \
        (const __attribute__((address_space(1))) void*)(src),                        \
        (__attribute__((address_space(3))) void*)(dst), 16, 0, 0)

#define AST64(j, bb)                                                                 \
    do {                                                                             \
        const ushort* kg0 = kbase + (size_t)(j) * 64 * QKVN;                         \
        const ushort* kg1 = kg0 + (size_t)32 * QKVN;                                 \
        GLD(kg0,      ldsK + (bb) * 16384 + (2 * w) * 1024);                         \
        GLD(kg0 + 16, ldsK + (bb) * 16384 + (2 * w + 1) * 1024);                     \
        GLD(kg1,      ldsK + (bb) * 16384 + (8 + 2 * w) * 1024);                     \
        GLD(kg1 + 16, ldsK + (bb) * 16384 + (8 + 2 * w + 1) * 1024);                 \
        const ushort* vg = vbase + (j) * 64;                                         \
        GLD(vg,       ldsV + (bb) * 16384 + (4 * w + 0) * 1024);                     \
        GLD(vg + 16,  ldsV + (bb) * 16384 + (4 * w + 1) * 1024);                     \
        GLD(vg + 32,  ldsV + (bb) * 16384 + (4 * w + 2) * 1024);                     \
        GLD(vg + 48,  ldsV + (bb) * 16384 + (4 * w + 3) * 1024);                     \
    } while (0)

    AST64(0, 0);   // prologue: stage tile 0 into buf 0

    for (int j = 0; j < nst; j++) {
        const int buf = j & 1;
        __builtin_amdgcn_s_barrier();            // all waves done computing j-1
        if (j + 1 < nst) {
            AST64(j + 1, buf ^ 1);
            asm volatile("s_waitcnt vmcnt(8)" ::: "memory");   // tile j's loads landed
        } else {
            asm volatile("s_waitcnt vmcnt(0)" ::: "memory");
        }
        __builtin_amdgcn_s_barrier();            // everyone's tile-j loads visible

        if (j <= mylast) {  // wave-uniform predicate (w-dependent)
            const ushort* Kb = &Kf[buf][0];
            const ushort* Vb = &Vf[buf][0];
            f32x16 S0, S1;
#pragma unroll
            for (int r = 0; r < 16; r++) { S0[r] = 0.f; S1[r] = 0.f; }
            __builtin_amdgcn_s_setprio(1);
#pragma unroll
            for (int kt = 0; kt < 8; kt++) {
                short8 k0 = *(const short8*)(Kb + kt * 512 + l * 8);
                S0 = __builtin_amdgcn_mfma_f32_32x32x16_bf16(k0, qf[kt], S0, 0, 0, 0);
            }
#pragma unroll
            for (int kt = 0; kt < 8; kt++) {
                short8 k1 = *(const short8*)(Kb + (8 + kt) * 512 + l * 8);
                S1 = __builtin_amdgcn_mfma_f32_32x32x16_bf16(k1, qf[kt], S1, 0, 0, 0);
            }
            __builtin_amdgcn_s_setprio(0);

            if (j == mylast) {
                const int sb = j * 64 + 4 * hf;
#pragma unroll
                for (int r = 0; r < 16; r++) {
                    const int sg = sb + (r & 3) + 8 * (r >> 2);
                    if (sg > qg) S0[r] = -INFINITY;
                    if (sg + 32 > qg) S1[r] = -INFINITY;
                }
            }
            float rmax = S0[0];
#pragma unroll
            for (int r = 1; r < 16; r++) rmax = fmaxf(rmax, S0[r]);
#pragma unroll
            for (int r = 0; r < 16; r++) rmax = fmaxf(rmax, S1[r]);
            rmax = fmaxf(rmax, __shfl_xor(rmax, 32));

            // ---- defer-max (T13) ----
            const unsigned long long need = __ballot(rmax > mcur + 8.0f);
            float mnew, alpha;
            if (need == 0) { mnew = mcur; alpha = 1.0f; }
            else { mnew = fmaxf(mcur, rmax); alpha = __expf(mcur - mnew); }

            float rsum = 0.f;
#pragma unroll
            for (int r = 0; r < 16; r++) {
                S0[r] = __expf(S0[r] - mnew);
                rsum += S0[r];
            }
#pragma unroll
            for (int r = 0; r < 16; r++) {
                S1[r] = __expf(S1[r] - mnew);
                rsum += S1[r];
            }
            rsum += __shfl_xor(rsum, 32);
            lcur = lcur * alpha + rsum;
            mcur = mnew;

            if (need != 0) {
#pragma unroll
                for (int dt = 0; dt < 4; dt++)
#pragma unroll
                    for (int r = 0; r < 16; r++) O[dt][r] *= alpha;
            }

            short8 Pf[4];
            {
                unsigned pk[8], rk[8];
#pragma unroll
                for (int g = 0; g < 4; g++) {
                    pk[2 * g]     = (unsigned)f2bf(S0[4 * g])     | ((unsigned)f2bf(S0[4 * g + 1]) << 16);
                    pk[2 * g + 1] = (unsigned)f2bf(S0[4 * g + 2]) | ((unsigned)f2bf(S0[4 * g + 3]) << 16);
                }
#pragma unroll
                for (int i = 0; i < 8; i++) rk[i] = (unsigned)__shfl_xor((int)pk[i], 32);
#pragma unroll
                for (int kt2 = 0; kt2 < 2; kt2++) {
                    const int g = 2 * kt2 + hf;
                    union { unsigned u[4]; short8 s; } cvt;
                    cvt.u[0] = hf ? rk[2 * g]     : pk[2 * g];
                    cvt.u[1] = hf ? rk[2 * g + 1] : pk[2 * g + 1];
                    cvt.u[2] = hf ? pk[2 * g]     : rk[2 * g];
                    cvt.u[3] = hf ? pk[2 * g + 1] : rk[2 * g + 1];
                    Pf[kt2] = cvt.s;
                }
#pragma unroll
                for (int g = 0; g < 4; g++) {
                    pk[2 * g]     = (unsigned)f2bf(S1[4 * g])     | ((unsigned)f2bf(S1[4 * g + 1]) << 16);
                    pk[2 * g + 1] = (unsigned)f2bf(S1[4 * g + 2]) | ((unsigned)f2bf(S1[4 * g + 3]) << 16);
                }
#pragma unroll
                for (int i = 0; i < 8; i++) rk[i] = (unsigned)__shfl_xor((int)pk[i], 32);
#pragma unroll
                for (int kt2 = 0; kt2 < 2; kt2++) {
                    const int g = 2 * kt2 + hf;
                    union { unsigned u[4]; short8 s; } cvt;
                    cvt.u[0] = hf ? rk[2 * g]     : pk[2 * g];
                    cvt.u[1] = hf ? rk[2 * g + 1] : pk[2 * g + 1];
                    cvt.u[2] = hf ? pk[2 * g]     : rk[2 * g];
                    cvt.u[3] = hf ? pk[2 * g + 1] : rk[2 * g + 1];
                    Pf[2 + kt2] = cvt.s;
                }
            }

            __builtin_amdgcn_s_setprio(1);
#pragma unroll
            for (int dt = 0; dt < 4; dt++)
#pragma unroll
                for (int ks = 0; ks < 4; ks++) {
                    short8 afV = *(const short8*)(Vb + (dt * 4 + ks) * 512 + l * 8);
                    O[dt] = __builtin_amdgcn_mfma_f32_32x32x16_bf16(afV, Pf[ks], O[dt], 0, 0, 0);
                }
            __builtin_amdgcn_s_setprio(0);
        }
    }
#undef AST64
#undef GLD

    const float inv = 1.0f / lcur;
    ushort* orow = attnB + (size_t)qg * HDIM + h * HD + 4 * hf;
#pragma unroll
    for (int dt = 0; dt < 4; dt++)
#pragma unroll
        for (int rg = 0; rg < 4; rg++) {
            ushort4 o;
            o.x = f2bf(O[dt][4 * rg + 0] * inv);
            o.y = f2bf(O[dt][4 * rg + 1] * inv);
            o.z = f2bf(O[dt][4 * rg + 2] * inv);
            o.w = f2bf(O[dt][4 * rg + 3] * inv);
            *(ushort4*)(orow + dt * 32 + 8 * rg) = o;
        }
}

// ---------------------------------------------------------------------------
// Fallback fp32 path — used only if workspace is too small.
// ---------------------------------------------------------------------------
__global__ __launch_bounds__(256) void rope_kernel(const int* __restrict__ pos,
                                                   float* __restrict__ qkv) {
    const int t = blockIdx.x;
    const int head = blockIdx.y * 4 + (threadIdx.x >> 6);
    const int d = threadIdx.x & 63;
    const float p = (float)pos[t];
    const float invf = exp2f(-(float)d * (19.931568569324174f / 64.0f));
    const float f = p * invf;
    const float c = cosf(f), s = sinf(f);
    float* base = qkv + (size_t)t * QKVN + head * HD;
    const float x1 = base[d];
    const float x2 = base[d + 64];
    base[d]      = x1 * c - x2 * s;
    base[d + 64] = x2 * c + x1 * s;
}

#define DOT4(acc, a, b) acc += (a).x*(b).x + (a).y*(b).y + (a).z*(b).z + (a).w*(b).w
#define FMA4(o, p, v) { (o).x += (p)*(v).x; (o).y += (p)*(v).y; (o).z += (p)*(v).z; (o).w += (p)*(v).w; }

__global__ __launch_bounds__(256, 2) void flash_attn_f32(const float* __restrict__ qkv,
                                                         float* __restrict__ out) {
    __shared__ float Qs[64 * 132];
    __shared__ float KVs[32 * 132];
    __shared__ float Ps[64 * 34];
    const int b = blockIdx.x;
    const int half = (b >> 9) & 1;
    const int rest = b & 511;
    const int h = rest >> 4;
    const int qlo = rest & 15;
    const int qi = half ? (31 - qlo) : qlo;
    const int kvh = h >> 2;
    const int tid = threadIdx.x;
    const int tx = tid & 7;
    const int ty = tid >> 3;
    {
        const float* qbase = qkv + (size_t)(qi * 64) * QKVN + h * HD;
#pragma unroll
        for (int r = 0; r < 8; r++) {
            int idx = r * 256 + tid;
            int qrow = idx >> 5;
            int d = (idx & 31) * 4;
            float4 v = *(const float4*)(qbase + (size_t)qrow * QKVN + d);
            v.x *= SCALE; v.y *= SCALE; v.z *= SCALE; v.w *= SCALE;
            *(float4*)(Qs + qrow * 132 + d) = v;
        }
    }
    float m[2], lsm[2];
    float4 O[2][4];
#pragma unroll
    for (int i = 0; i < 2; i++) {
        m[i] = -INFINITY; lsm[i] = 0.f;
#pragma unroll
        for (int jj = 0; jj < 4; jj++) O[i][jj] = make_float4(0.f, 0.f, 0.f, 0.f);
    }
    const float* kbase = qkv + KV_OFF + kvh * HD;
    const float* vbase = qkv + V_OFF + kvh * HD;
    const int qg0 = qi * 64 + ty;
    const int nst = 2 * qi + 2;
    for (int st = 0; st < nst; st++) {
        __syncthreads();
#pragma unroll
        for (int r = 0; r < 4; r++) {
            int idx = r * 256 + tid;
            int srow = idx >> 5;
            int d = (idx & 31) * 4;
            *(float4*)(KVs + srow * 132 + d) =
                *(const float4*)(kbase + (size_t)(st * 32 + srow) * QKVN + d);
        }
        __syncthreads();
        float S[2][4];
#pragma unroll
        for (int i = 0; i < 2; i++)
#pragma unroll
            for (int j = 0; j < 4; j++) S[i][j] = 0.f;
#pragma unroll 4
        for (int kk = 0; kk < HD; kk += 4) {
            float4 q0 = *(const float4*)(Qs + ty * 132 + kk);
            float4 q1 = *(const float4*)(Qs + (ty + 32) * 132 + kk);
            float4 k0 = *(const float4*)(KVs + tx * 132 + kk);
            float4 k1 = *(const float4*)(KVs + (tx + 8) * 132 + kk);
            float4 k2 = *(const float4*)(KVs + (tx + 16) * 132 + kk);
            float4 k3 = *(const float4*)(KVs + (tx + 24) * 132 + kk);
            DOT4(S[0][0], q0, k0); DOT4(S[0][1], q0, k1);
            DOT4(S[0][2], q0, k2); DOT4(S[0][3], q0, k3);
            DOT4(S[1][0], q1, k0); DOT4(S[1][1], q1, k1);
            DOT4(S[1][2], q1, k2); DOT4(S[1][3], q1, k3);
        }
        const int sg0 = st * 32 + tx;
        float alpha[2];
#pragma unroll
        for (int i = 0; i < 2; i++) {
            const int qg = qg0 + 32 * i;
            float rmax = -INFINITY;
#pragma unroll
            for (int j = 0; j < 4; j++) {
                if (sg0 + 8 * j > qg) S[i][j] = -INFINITY;
                rmax = fmaxf(rmax, S[i][j]);
            }
#pragma unroll
            for (int off = 1; off < 8; off <<= 1)
                rmax = fmaxf(rmax, __shfl_xor(rmax, off));
            const float mnew = fmaxf(m[i], rmax);
            alpha[i] = __expf(m[i] - mnew);
            float rsum = 0.f;
#pragma unroll
            for (int j = 0; j < 4; j++) {
                S[i][j] = __expf(S[i][j] - mnew);
                rsum += S[i][j];
            }
#pragma unroll
            for (int off = 1; off < 8; off <<= 1)
                rsum += __shfl_xor(rsum, off);
            lsm[i] = lsm[i] * alpha[i] + rsum;
            m[i] = mnew;
        }
#pragma unroll
        for (int i = 0; i < 2; i++)
#pragma unroll
            for (int j = 0; j < 4; j++)
                Ps[(ty + 32 * i) * 34 + tx + 8 * j] = S[i][j];
        __syncthreads();
#pragma unroll
        for (int r = 0; r < 4; r++) {
            int idx = r * 256 + tid;
            int srow = idx >> 5;
            int d = (idx & 31) * 4;
            *(float4*)(KVs + srow * 132 + d) =
                *(const float4*)(vbase + (size_t)(st * 32 + srow) * QKVN + d);
        }
        __syncthreads();
#pragma unroll
        for (int i = 0; i < 2; i++) {
            const float a = alpha[i];
#pragma unroll
            for (int jj = 0; jj < 4; jj++) {
                O[i][jj].x *= a; O[i][jj].y *= a; O[i][jj].z *= a; O[i][jj].w *= a;
            }
        }
#pragma unroll 4
        for (int s = 0; s < 32; s++) {
            float p0 = Ps[ty * 34 + s];
            float p1 = Ps[(ty + 32) * 34 + s];
            const float* vr = KVs + s * 132 + 4 * tx;
            float4 v0 = *(const float4*)(vr);
            float4 v1 = *(const float4*)(vr + 32);
            float4 v2 = *(const float4*)(vr + 64);
            float4 v3 = *(const float4*)(vr + 96);
            FMA4(O[0][0], p0, v0); FMA4(O[0][1], p0, v1);
            FMA4(O[0][2], p0, v2); FMA4(O[0][3], p0, v3);
            FMA4(O[1][0], p1, v0); FMA4(O[1][1], p1, v1);
            FMA4(O[1][2], p1, v2); FMA4(O[1][3], p1, v3);
        }
    }
#pragma unroll
    for (int i = 0; i < 2; i++) {
        const float inv = 1.0f / lsm[i];
        float* orow = out + (size_t)(qi * 64 + ty + 32 * i) * HDIM + h * HD + 4 * tx;
#pragma unroll
        for (int jj = 0; jj < 4; jj++) {
            float4 wv = O[i][jj];
            wv.x *= inv; wv.y *= inv; wv.z *= inv; wv.w *= inv;
            *(float4*)(orow + 32 * jj) = wv;
        }
    }
}

template <int N_, int K_>
__global__ __launch_bounds__(256) void sgemm(const float* __restrict__ A,
                                             const float* __restrict__ B,
                                             float* __restrict__ C) {
    __shared__ float As[8][128];
    __shared__ float Bs[8][128];
    const int tid = threadIdx.x;
    const int bm = blockIdx.y * 128;
    const int bn = blockIdx.x * 128;
    const int tx = tid & 15;
    const int ty = tid >> 4;
    const int lm = tid >> 1;
    const int lkq = (tid & 1) * 4;
    const int lr = tid >> 5;
    const int lnq = (tid & 31) * 4;
    float acc[8][8];
#pragma unroll
    for (int i = 0; i < 8; i++)
#pragma unroll
        for (int j = 0; j < 8; j++) acc[i][j] = 0.f;
    const float* Aptr = A + (size_t)(bm + lm) * K_ + lkq;
    const float* Bptr = B + (size_t)lr * N_ + bn + lnq;
    for (int k0 = 0; k0 < K_; k0 += 8) {
        float4 av = *(const float4*)Aptr;
        float4 bv = *(const float4*)Bptr;
        __syncthreads();
        As[lkq + 0][lm] = av.x;
        As[lkq + 1][lm] = av.y;
        As[lkq + 2][lm] = av.z;
        As[lkq + 3][lm] = av.w;
        *(float4*)&Bs[lr][lnq] = bv;
        __syncthreads();
        Aptr += 8;
        Bptr += (size_t)8 * N_;
#pragma unroll
        for (int kk = 0; kk < 8; kk++) {
            float4 a0 = *(const float4*)&As[kk][ty * 4];
            float4 a1 = *(const float4*)&As[kk][64 + ty * 4];
            float4 b0 = *(const float4*)&Bs[kk][tx * 4];
            float4 b1 = *(const float4*)&Bs[kk][64 + tx * 4];
            float a[8] = {a0.x, a0.y, a0.z, a0.w, a1.x, a1.y, a1.z, a1.w};
            float bb[8] = {b0.x, b0.y, b0.z, b0.w, b1.x, b1.y, b1.z, b1.w};
#pragma unroll
            for (int i = 0; i < 8; i++)
#pragma unroll
                for (int j = 0; j < 8; j++) acc[i][j] += a[i] * bb[j];
        }
    }
#pragma unroll
    for (int i = 0; i < 8; i++) {
        int row = bm + ((i < 4) ? (ty * 4 + i) : (64 + ty * 4 + i - 4));
        float4 c0 = {acc[i][0], acc[i][1], acc[i][2], acc[i][3]};
        float4 c1 = {acc[i][4], acc[i][5], acc[i][6], acc[i][7]};
        *(float4*)&C[(size_t)row * N_ + bn + tx * 4] = c0;
        *(float4*)&C[(size_t)row * N_ + bn + 64 + tx * 4] = c1;
    }
}

// ---------------------------------------------------------------------------
extern "C" void kernel_launch(void* const* d_in, const int* in_sizes, int n_in,
                              void* d_out, int out_size, void* d_ws, size_t ws_size,
                              hipStream_t stream) {
    const int*   positions = (const int*)d_in[0];
    const float* hidden    = (const float*)d_in[1];
    const float* Wqkv      = (const float*)d_in[2];
    const float* Wo        = (const float*)d_in[3];
    float* out = (float*)d_out;

    char* ws = (char*)d_ws;
    ushort* qkB   = (ushort*)ws;                    // [0, 25165824)
    ushort* Vt    = (ushort*)(ws + 25165824);       // [25165824, 29360128)
    ushort* attnB = (ushort*)(ws + 29360128);       // [29360128, 46137344)
    ushort* WqkvT = (ushort*)(ws + 50331648);       // [50331648, 100663296) dead after gemm1
    ushort* WoT   = (ushort*)(ws + 100663296);      // [100663296, 134217728)
    ushort* hA    = (ushort*)(ws + 134217728);      // [134217728, 150994944) dead after gemm1
    const size_t NEEDED = 163577856;

    if (ws_size >= NEEDED) {
        cast_bf16<<<dim3((T_TOK * HDIM) / 1024), 256, 0, stream>>>(hidden, hA);
        transpose_cast<HDIM, QKVN><<<dim3(QKVN / 64, HDIM / 64), 256, 0, stream>>>(Wqkv, WqkvT);
        transpose_cast<HDIM, HDIM><<<dim3(HDIM / 64, HDIM / 64), 256, 0, stream>>>(Wo, WoT);
        gemm_bf16_8ph<QKVN, HDIM, HDIM, 1>
            <<<dim3((T_TOK / 256) * (QKVN / 256), 1), 512, 0, stream>>>(
                hA, WqkvT, nullptr, nullptr, positions, qkB, Vt);
        flash_attn_mfma<<<dim3(512), 256, 0, stream>>>(qkB, Vt, attnB);
        gemm_bf16_n128<HDIM, HDIM, HDIM>
            <<<dim3((T_TOK / 256) * (HDIM / 128)), 512, 0, stream>>>(attnB, WoT, out);
    } else {
        float* qkv  = (float*)ws;
        float* attn = qkv + (size_t)T_TOK * QKVN;
        sgemm<QKVN, HDIM><<<dim3(QKVN / 128, T_TOK / 128), 256, 0, stream>>>(hidden, Wqkv, qkv);
        rope_kernel<<<dim3(T_TOK, 10), 256, 0, stream>>>(positions, qkv);
        flash_attn_f32<<<dim3(1024), 256, 0, stream>>>(qkv, attn);
        sgemm<HDIM, HDIM><<<dim3(HDIM / 128, T_TOK / 128), 256, 0, stream>>>(attn, Wo, out);
    }
}